// Round 1
// baseline (2204.546 us; speedup 1.0000x reference)
//
#include <hip/hip_runtime.h>
#include <math.h>

#define N_NODES 100000
#define N_EDGES 1600000
#define NG      128
#define HD      256
#define PHD     128
#define GFD     32
#define XW      241
#define LN_EPS  1e-5f

static __device__ __forceinline__ float relu_f(float x){ return fmaxf(x, 0.0f); }

// h[i] = [x[i,1:241], emb_table[(int)x[i,0]]]  -- one block (256 thr) per node
__global__ void build_h_kernel(const float* __restrict__ x, const float* __restrict__ emb,
                               float* __restrict__ h)
{
    int node = blockIdx.x;
    int tid  = threadIdx.x;
    const float* xr = x + (size_t)node * XW;
    float v;
    if (tid < 240) {
        v = xr[1 + tid];
    } else {
        int t = (int)xr[0];
        v = emb[t * 16 + (tid - 240)];
    }
    h[(size_t)node * HD + tid] = v;
}

__global__ void count_deg_kernel(const int* __restrict__ dst, int* __restrict__ cnt, int e)
{
    int i = blockIdx.x * blockDim.x + threadIdx.x;
    if (i < e) atomicAdd(&cnt[dst[i]], 1);
}

// single-block exclusive scan: cursor holds degrees on entry; on exit rowptr[i]=prefix,
// cursor[i]=prefix (fill cursors), rowptr[n]=total
__global__ void scan_kernel(int* __restrict__ cursor, int* __restrict__ rowptr, int n)
{
    __shared__ int tot[1024];
    int tid = threadIdx.x;
    int chunk = (n + 1023) >> 10;
    int beg = tid * chunk; if (beg > n) beg = n;
    int end = beg + chunk; if (end > n) end = n;
    int s = 0;
    for (int i = beg; i < end; i++) s += cursor[i];
    tot[tid] = s;
    __syncthreads();
    for (int off = 1; off < 1024; off <<= 1) {
        int v = tot[tid];
        int add = (tid >= off) ? tot[tid - off] : 0;
        __syncthreads();
        tot[tid] = v + add;
        __syncthreads();
    }
    int run = (tid > 0) ? tot[tid - 1] : 0;
    for (int i = beg; i < end; i++) {
        int d = cursor[i];
        rowptr[i] = run;
        cursor[i] = run;
        run += d;
    }
    if (tid == 1023) rowptr[n] = tot[1023];
}

__global__ void fill_csr_kernel(const int* __restrict__ src, const int* __restrict__ dst,
                                int* __restrict__ cursor, int* __restrict__ col, int e)
{
    int i = blockIdx.x * blockDim.x + threadIdx.x;
    if (i < e) {
        int p = atomicAdd(&cursor[dst[i]], 1);
        col[p] = src[i];
    }
}

// z[i] = h[i] + sum_{j in CSR row i} h[col[j]]   -- one wave (64 lanes * float4) per node
__global__ __launch_bounds__(256) void aggregate_kernel(
    const float* __restrict__ h, const int* __restrict__ rowptr,
    const int* __restrict__ col, float* __restrict__ z, int n)
{
    int node = blockIdx.x * 4 + (threadIdx.x >> 6);
    int lane = threadIdx.x & 63;
    if (node >= n) return;
    size_t base = (size_t)node * HD + lane * 4;
    float4 acc = *(const float4*)&h[base];
    int e = rowptr[node], e1 = rowptr[node + 1];
    for (; e < e1; e++) {
        int s = col[e];
        const float4 v = *(const float4*)&h[(size_t)s * HD + lane * 4];
        acc.x += v.x; acc.y += v.y; acc.z += v.z; acc.w += v.w;
    }
    *(float4*)&z[base] = acc;
}

// h += relu(LN(relu(z@w1+b1)@w2 + b2))   -- 32 rows per block, 256 threads
// thread: 4 rows (ry=tid>>5) x 8 cols (cx=tid&31 -> cols 4cx..4cx+3, 128+4cx..)
__global__ __launch_bounds__(256, 2) void mlp_ln_res_kernel(
    float* __restrict__ h, const float* __restrict__ z,
    const float* __restrict__ w1, const float* __restrict__ b1,
    const float* __restrict__ w2, const float* __restrict__ b2,
    const float* __restrict__ lng, const float* __restrict__ lnb)
{
    __shared__ float zs[32][HD];
    __shared__ float ts[32][HD];
    const int tid = threadIdx.x;
    const size_t row0 = (size_t)blockIdx.x * 32;

    {
        const float4* zg = (const float4*)(z + row0 * HD);
        float4* zl = (float4*)&zs[0][0];
        #pragma unroll
        for (int i = 0; i < 8; i++) zl[tid + 256 * i] = zg[tid + 256 * i];
    }
    __syncthreads();

    const int cx = tid & 31;
    const int ry = tid >> 5;
    const int c0 = cx * 4, c1 = cx * 4 + 128;

    float acc[4][8];
    {
        const float4 ba = *(const float4*)&b1[c0];
        const float4 bb = *(const float4*)&b1[c1];
        #pragma unroll
        for (int r = 0; r < 4; r++) {
            acc[r][0] = ba.x; acc[r][1] = ba.y; acc[r][2] = ba.z; acc[r][3] = ba.w;
            acc[r][4] = bb.x; acc[r][5] = bb.y; acc[r][6] = bb.z; acc[r][7] = bb.w;
        }
    }
    for (int k = 0; k < HD; k += 4) {
        float4 zr[4];
        #pragma unroll
        for (int r = 0; r < 4; r++) zr[r] = *(const float4*)&zs[ry * 4 + r][k];
        #pragma unroll
        for (int kk = 0; kk < 4; kk++) {
            const float4 wa = *(const float4*)&w1[(k + kk) * HD + c0];
            const float4 wb = *(const float4*)&w1[(k + kk) * HD + c1];
            #pragma unroll
            for (int r = 0; r < 4; r++) {
                const float zv = kk == 0 ? zr[r].x : kk == 1 ? zr[r].y : kk == 2 ? zr[r].z : zr[r].w;
                acc[r][0] += zv * wa.x; acc[r][1] += zv * wa.y;
                acc[r][2] += zv * wa.z; acc[r][3] += zv * wa.w;
                acc[r][4] += zv * wb.x; acc[r][5] += zv * wb.y;
                acc[r][6] += zv * wb.z; acc[r][7] += zv * wb.w;
            }
        }
    }
    #pragma unroll
    for (int r = 0; r < 4; r++) {
        float4 ta = make_float4(relu_f(acc[r][0]), relu_f(acc[r][1]), relu_f(acc[r][2]), relu_f(acc[r][3]));
        float4 tb = make_float4(relu_f(acc[r][4]), relu_f(acc[r][5]), relu_f(acc[r][6]), relu_f(acc[r][7]));
        *(float4*)&ts[ry * 4 + r][c0] = ta;
        *(float4*)&ts[ry * 4 + r][c1] = tb;
    }
    __syncthreads();

    {
        const float4 ba = *(const float4*)&b2[c0];
        const float4 bb = *(const float4*)&b2[c1];
        #pragma unroll
        for (int r = 0; r < 4; r++) {
            acc[r][0] = ba.x; acc[r][1] = ba.y; acc[r][2] = ba.z; acc[r][3] = ba.w;
            acc[r][4] = bb.x; acc[r][5] = bb.y; acc[r][6] = bb.z; acc[r][7] = bb.w;
        }
    }
    for (int k = 0; k < HD; k += 4) {
        float4 zr[4];
        #pragma unroll
        for (int r = 0; r < 4; r++) zr[r] = *(const float4*)&ts[ry * 4 + r][k];
        #pragma unroll
        for (int kk = 0; kk < 4; kk++) {
            const float4 wa = *(const float4*)&w2[(k + kk) * HD + c0];
            const float4 wb = *(const float4*)&w2[(k + kk) * HD + c1];
            #pragma unroll
            for (int r = 0; r < 4; r++) {
                const float zv = kk == 0 ? zr[r].x : kk == 1 ? zr[r].y : kk == 2 ? zr[r].z : zr[r].w;
                acc[r][0] += zv * wa.x; acc[r][1] += zv * wa.y;
                acc[r][2] += zv * wa.z; acc[r][3] += zv * wa.w;
                acc[r][4] += zv * wb.x; acc[r][5] += zv * wb.y;
                acc[r][6] += zv * wb.z; acc[r][7] += zv * wb.w;
            }
        }
    }
    // write z2 into zs (all zs readers are past the barrier above)
    #pragma unroll
    for (int r = 0; r < 4; r++) {
        *(float4*)&zs[ry * 4 + r][c0] = make_float4(acc[r][0], acc[r][1], acc[r][2], acc[r][3]);
        *(float4*)&zs[ry * 4 + r][c1] = make_float4(acc[r][4], acc[r][5], acc[r][6], acc[r][7]);
    }
    __syncthreads();

    // LayerNorm + relu + residual: wave w handles rows 8w..8w+7
    const int wave = tid >> 6, lane = tid & 63;
    const float4 gv = *(const float4*)&lng[lane * 4];
    const float4 bv = *(const float4*)&lnb[lane * 4];
    for (int rr = 0; rr < 8; rr++) {
        int row = wave * 8 + rr;
        float4 v = *(const float4*)&zs[row][lane * 4];
        float s = v.x + v.y + v.z + v.w;
        float q = v.x * v.x + v.y * v.y + v.z * v.z + v.w * v.w;
        #pragma unroll
        for (int off = 32; off > 0; off >>= 1) {
            s += __shfl_xor(s, off, 64);
            q += __shfl_xor(q, off, 64);
        }
        float mu = s * (1.0f / 256.0f);
        float var = q * (1.0f / 256.0f) - mu * mu;
        float rstd = rsqrtf(var + LN_EPS);
        size_t gi = (row0 + row) * HD + lane * 4;
        float4 hv = *(float4*)&h[gi];
        hv.x += relu_f((v.x - mu) * rstd * gv.x + bv.x);
        hv.y += relu_f((v.y - mu) * rstd * gv.y + bv.y);
        hv.z += relu_f((v.z - mu) * rstd * gv.z + bv.z);
        hv.w += relu_f((v.w - mu) * rstd * gv.w + bv.w);
        *(float4*)&h[gi] = hv;
    }
}

// gate[i] = relu(h[i]@gw1+gb1)@gw2 + gb2   -- 32 rows per block
__global__ __launch_bounds__(256, 2) void gate_kernel(
    const float* __restrict__ h,
    const float* __restrict__ gw1, const float* __restrict__ gb1,
    const float* __restrict__ gw2, const float* __restrict__ gb2,
    float* __restrict__ gate)
{
    __shared__ float zs[32][HD];
    __shared__ float ts[32][PHD];
    const int tid = threadIdx.x;
    const size_t row0 = (size_t)blockIdx.x * 32;
    {
        const float4* zg = (const float4*)(h + row0 * HD);
        float4* zl = (float4*)&zs[0][0];
        #pragma unroll
        for (int i = 0; i < 8; i++) zl[tid + 256 * i] = zg[tid + 256 * i];
    }
    __syncthreads();

    const int cx = tid & 31;
    const int ry = tid >> 5;
    const int c0 = cx * 4;

    float acc[4][4];
    {
        const float4 ba = *(const float4*)&gb1[c0];
        #pragma unroll
        for (int r = 0; r < 4; r++) {
            acc[r][0] = ba.x; acc[r][1] = ba.y; acc[r][2] = ba.z; acc[r][3] = ba.w;
        }
    }
    for (int k = 0; k < HD; k += 4) {
        float4 zr[4];
        #pragma unroll
        for (int r = 0; r < 4; r++) zr[r] = *(const float4*)&zs[ry * 4 + r][k];
        #pragma unroll
        for (int kk = 0; kk < 4; kk++) {
            const float4 wa = *(const float4*)&gw1[(k + kk) * PHD + c0];
            #pragma unroll
            for (int r = 0; r < 4; r++) {
                const float zv = kk == 0 ? zr[r].x : kk == 1 ? zr[r].y : kk == 2 ? zr[r].z : zr[r].w;
                acc[r][0] += zv * wa.x; acc[r][1] += zv * wa.y;
                acc[r][2] += zv * wa.z; acc[r][3] += zv * wa.w;
            }
        }
    }
    #pragma unroll
    for (int r = 0; r < 4; r++) {
        *(float4*)&ts[ry * 4 + r][c0] =
            make_float4(relu_f(acc[r][0]), relu_f(acc[r][1]), relu_f(acc[r][2]), relu_f(acc[r][3]));
    }
    __syncthreads();

    const int wave = tid >> 6, lane = tid & 63;
    const float2 wv = *(const float2*)&gw2[lane * 2];
    const float b2v = gb2[0];
    for (int rr = 0; rr < 8; rr++) {
        int row = wave * 8 + rr;
        float2 t2 = *(const float2*)&ts[row][lane * 2];
        float p = t2.x * wv.x + t2.y * wv.y;
        #pragma unroll
        for (int off = 32; off > 0; off >>= 1) p += __shfl_xor(p, off, 64);
        if (lane == 0) gate[row0 + row] = p + b2v;
    }
}

// goff[g] = lower_bound(batch, g)
__global__ void goff_kernel(const int* __restrict__ batch, int* __restrict__ goff, int n)
{
    int t = threadIdx.x;
    if (t > NG) return;
    int lo = 0, hi = n;
    while (lo < hi) {
        int mid = (lo + hi) >> 1;
        if (batch[mid] < t) lo = mid + 1; else hi = mid;
    }
    goff[t] = lo;
}

// softmax-weighted pooling per graph (one block per graph, 256 threads = 256 cols)
__global__ __launch_bounds__(256) void pool_kernel(
    const float* __restrict__ h, const float* __restrict__ gate,
    const int* __restrict__ goff, float* __restrict__ a_scratch,
    float* __restrict__ pooled)
{
    __shared__ float red[256];
    __shared__ float m_sh, s_sh;
    int g = blockIdx.x, tid = threadIdx.x;
    int beg = goff[g], end = goff[g + 1];
    if (beg >= end) { pooled[(size_t)g * HD + tid] = 0.0f; return; }

    float lm = -3.4e38f;
    for (int i = beg + tid; i < end; i += 256) lm = fmaxf(lm, gate[i]);
    red[tid] = lm; __syncthreads();
    for (int off = 128; off > 0; off >>= 1) {
        if (tid < off) red[tid] = fmaxf(red[tid], red[tid + off]);
        __syncthreads();
    }
    if (tid == 0) m_sh = red[0];
    __syncthreads();
    float m = m_sh;

    float ls = 0.0f;
    for (int i = beg + tid; i < end; i += 256) {
        float a = expf(gate[i] - m);
        a_scratch[i] = a;
        ls += a;
    }
    __syncthreads();
    red[tid] = ls; __syncthreads();
    for (int off = 128; off > 0; off >>= 1) {
        if (tid < off) red[tid] += red[tid + off];
        __syncthreads();
    }
    if (tid == 0) s_sh = red[0];
    __syncthreads();
    float inv_s = 1.0f / s_sh;

    float acc = 0.0f;
    for (int i = beg; i < end; i++) {
        acc += a_scratch[i] * h[(size_t)i * HD + tid];
    }
    pooled[(size_t)g * HD + tid] = acc * inv_s;
}

// out[g] = relu([pooled,gf]@cw1+cb1)@cw2 + cb2   -- one block per graph, 128 threads
__global__ __launch_bounds__(128) void cls_kernel(
    const float* __restrict__ pooled, const float* __restrict__ gf,
    const float* __restrict__ w1, const float* __restrict__ b1,
    const float* __restrict__ w2, const float* __restrict__ b2,
    float* __restrict__ out)
{
    __shared__ float r0[128], r1[128];
    int g = blockIdx.x, c = threadIdx.x;
    float acc = b1[c];
    const float* pr = pooled + (size_t)g * HD;
    for (int k = 0; k < HD; k++) acc += pr[k] * w1[k * PHD + c];
    const float* gr = gf + g * GFD;
    for (int k = 0; k < GFD; k++) acc += gr[k] * w1[(HD + k) * PHD + c];
    float t = relu_f(acc);
    r0[c] = t * w2[c * 2 + 0];
    r1[c] = t * w2[c * 2 + 1];
    __syncthreads();
    for (int off = 64; off > 0; off >>= 1) {
        if (c < off) { r0[c] += r0[c + off]; r1[c] += r1[c + off]; }
        __syncthreads();
    }
    if (c == 0) {
        out[g * 2 + 0] = r0[0] + b2[0];
        out[g * 2 + 1] = r1[0] + b2[1];
    }
}

extern "C" void kernel_launch(void* const* d_in, const int* in_sizes, int n_in,
                              void* d_out, int out_size, void* d_ws, size_t ws_size,
                              hipStream_t stream)
{
    const float* x    = (const float*)d_in[0];
    const int*   ei   = (const int*)d_in[1];
    const int*   bat  = (const int*)d_in[2];
    const float* gf   = (const float*)d_in[3];
    const float* emb  = (const float*)d_in[4];
    const float* l0w1 = (const float*)d_in[5];
    const float* l0b1 = (const float*)d_in[6];
    const float* l0w2 = (const float*)d_in[7];
    const float* l0b2 = (const float*)d_in[8];
    const float* ln0g = (const float*)d_in[9];
    const float* ln0b = (const float*)d_in[10];
    const float* l1w1 = (const float*)d_in[11];
    const float* l1b1 = (const float*)d_in[12];
    const float* l1w2 = (const float*)d_in[13];
    const float* l1b2 = (const float*)d_in[14];
    const float* ln1g = (const float*)d_in[15];
    const float* ln1b = (const float*)d_in[16];
    const float* gw1  = (const float*)d_in[17];
    const float* gb1  = (const float*)d_in[18];
    const float* gw2  = (const float*)d_in[19];
    const float* gb2  = (const float*)d_in[20];
    const float* cw1  = (const float*)d_in[21];
    const float* cb1  = (const float*)d_in[22];
    const float* cw2  = (const float*)d_in[23];
    const float* cb2  = (const float*)d_in[24];

    char* ws = (char*)d_ws;
    size_t off = 0;
    auto alloc = [&](size_t bytes) {
        void* p = ws + off;
        off += (bytes + 255) & ~(size_t)255;
        return p;
    };
    float* h      = (float*)alloc((size_t)N_NODES * HD * 4);
    float* z      = (float*)alloc((size_t)N_NODES * HD * 4);
    float* gate   = (float*)alloc((size_t)N_NODES * 4);
    int*   rowptr = (int*)alloc((size_t)(N_NODES + 1) * 4);
    int*   cursor = (int*)alloc((size_t)N_NODES * 4);
    int*   col    = (int*)alloc((size_t)N_EDGES * 4);
    int*   goff   = (int*)alloc((NG + 1) * 4);
    float* pooled = (float*)alloc((size_t)NG * HD * 4);

    const int* src = ei;
    const int* dst = ei + N_EDGES;

    build_h_kernel<<<N_NODES, 256, 0, stream>>>(x, emb, h);

    hipMemsetAsync(cursor, 0, (size_t)N_NODES * 4, stream);
    count_deg_kernel<<<(N_EDGES + 255) / 256, 256, 0, stream>>>(dst, cursor, N_EDGES);
    scan_kernel<<<1, 1024, 0, stream>>>(cursor, rowptr, N_NODES);
    fill_csr_kernel<<<(N_EDGES + 255) / 256, 256, 0, stream>>>(src, dst, cursor, col, N_EDGES);

    // GIN block 0
    aggregate_kernel<<<N_NODES / 4, 256, 0, stream>>>(h, rowptr, col, z, N_NODES);
    mlp_ln_res_kernel<<<N_NODES / 32, 256, 0, stream>>>(h, z, l0w1, l0b1, l0w2, l0b2, ln0g, ln0b);
    // GIN block 1
    aggregate_kernel<<<N_NODES / 4, 256, 0, stream>>>(h, rowptr, col, z, N_NODES);
    mlp_ln_res_kernel<<<N_NODES / 32, 256, 0, stream>>>(h, z, l1w1, l1b1, l1w2, l1b2, ln1g, ln1b);

    gate_kernel<<<N_NODES / 32, 256, 0, stream>>>(h, gw1, gb1, gw2, gb2, gate);
    goff_kernel<<<1, 256, 0, stream>>>(bat, goff, N_NODES);
    pool_kernel<<<NG, 256, 0, stream>>>(h, gate, goff, z, pooled);
    cls_kernel<<<NG, 128, 0, stream>>>(pooled, gf, cw1, cb1, cw2, cb2, (float*)d_out);
}

// Round 2
// 1889.514 us; speedup vs baseline: 1.1667x; 1.1667x over previous
//
#include <hip/hip_runtime.h>
#include <math.h>

#define N_NODES 100000
#define N_EDGES 1600000
#define NG      128
#define HD      256
#define PHD     128
#define GFD     32
#define XW      241
#define LN_EPS  1e-5f
#define MT      64   // rows per MFMA block

typedef __attribute__((ext_vector_type(8))) short bf8_t;  // 8 bf16 (4 VGPR)
typedef __attribute__((ext_vector_type(4))) float f4_t;   // 4 f32 acc

static __device__ __forceinline__ float relu_f(float x){ return fmaxf(x, 0.0f); }

static __device__ __forceinline__ unsigned short f2bf_rn(float v) {
    unsigned int u = __float_as_uint(v);
    unsigned int r = (u + 0x7fffu + ((u >> 16) & 1u)) >> 16;
    return (unsigned short)r;
}
static __device__ __forceinline__ float bf2f(unsigned short h) {
    return __uint_as_float((unsigned int)h << 16);
}

// ---------------- h build ----------------
__global__ void build_h_kernel(const float* __restrict__ x, const float* __restrict__ emb,
                               float* __restrict__ h)
{
    int node = blockIdx.x;
    int tid  = threadIdx.x;
    const float* xr = x + (size_t)node * XW;
    float v;
    if (tid < 240) {
        v = xr[1 + tid];
    } else {
        int t = (int)xr[0];
        v = emb[t * 16 + (tid - 240)];
    }
    h[(size_t)node * HD + tid] = v;
}

// ---------------- CSR build ----------------
__global__ void count_deg_kernel(const int* __restrict__ dst, int* __restrict__ cnt, int e)
{
    int i = blockIdx.x * blockDim.x + threadIdx.x;
    if (i < e) atomicAdd(&cnt[dst[i]], 1);
}

__global__ void scan_kernel(int* __restrict__ cursor, int* __restrict__ rowptr, int n)
{
    __shared__ int tot[1024];
    int tid = threadIdx.x;
    int chunk = (n + 1023) >> 10;
    int beg = tid * chunk; if (beg > n) beg = n;
    int end = beg + chunk; if (end > n) end = n;
    int s = 0;
    for (int i = beg; i < end; i++) s += cursor[i];
    tot[tid] = s;
    __syncthreads();
    for (int off = 1; off < 1024; off <<= 1) {
        int v = tot[tid];
        int add = (tid >= off) ? tot[tid - off] : 0;
        __syncthreads();
        tot[tid] = v + add;
        __syncthreads();
    }
    int run = (tid > 0) ? tot[tid - 1] : 0;
    for (int i = beg; i < end; i++) {
        int d = cursor[i];
        rowptr[i] = run;
        cursor[i] = run;
        run += d;
    }
    if (tid == 1023) rowptr[n] = tot[1023];
}

__global__ void fill_csr_kernel(const int* __restrict__ src, const int* __restrict__ dst,
                                int* __restrict__ cursor, int* __restrict__ col, int e)
{
    int i = blockIdx.x * blockDim.x + threadIdx.x;
    if (i < e) {
        int p = atomicAdd(&cursor[dst[i]], 1);
        col[p] = src[i];
    }
}

// ---------------- aggregate: z = h + sum_neighbors h ----------------
__global__ __launch_bounds__(256) void aggregate_kernel(
    const float* __restrict__ h, const int* __restrict__ rowptr,
    const int* __restrict__ col, float* __restrict__ z, int n)
{
    int node = blockIdx.x * 4 + (threadIdx.x >> 6);
    int lane = threadIdx.x & 63;
    if (node >= n) return;
    size_t base = (size_t)node * HD + lane * 4;
    float4 acc = *(const float4*)&h[base];
    int e = rowptr[node], e1 = rowptr[node + 1];
    for (; e < e1; e++) {
        int s = col[e];
        const float4 v = *(const float4*)&h[(size_t)s * HD + lane * 4];
        acc.x += v.x; acc.y += v.y; acc.z += v.z; acc.w += v.w;
    }
    *(float4*)&z[base] = acc;
}

// ---------------- weight packing into B-fragment layout (hi/lo bf16) ----------------
// w is [K][N] f32 row-major. frag f = nb*(K/32)+kb; lane holds n=nb*16+(lane&15),
// k = kb*32 + (lane>>4)*8 + j, j=0..7, stored contiguously: out[f*512 + lane*8 + j].
__global__ void pack_w_kernel(const float* __restrict__ w, short* __restrict__ hi,
                              short* __restrict__ lo, int K, int N)
{
    int t = blockIdx.x * blockDim.x + threadIdx.x;
    int lane = t & 63;
    int f = t >> 6;
    int KB = K >> 5;
    int NB = N >> 4;
    if (f >= KB * NB) return;
    int nb = f / KB, kb = f % KB;
    int n = nb * 16 + (lane & 15);
    int k0 = kb * 32 + (lane >> 4) * 8;
    size_t o = (size_t)f * 512 + lane * 8;
    #pragma unroll
    for (int j = 0; j < 8; j++) {
        float v = w[(size_t)(k0 + j) * N + n];
        unsigned short hb = f2bf_rn(v);
        float hf = bf2f(hb);
        unsigned short lb = f2bf_rn(v - hf);
        hi[o + j] = (short)hb;
        lo[o + j] = (short)lb;
    }
}

// ---------------- fused MLP + LN + residual via split-bf16 MFMA ----------------
// h += relu(LN(relu(z@w1+b1)@w2 + b2)); 64 rows/block, 4 waves, wave w owns cols [64w,64w+64)
__global__ __launch_bounds__(256, 2) void mlp_mfma_kernel(
    float* __restrict__ h, const float* __restrict__ z,
    const short* __restrict__ w1h, const short* __restrict__ w1l, const float* __restrict__ b1,
    const short* __restrict__ w2h, const short* __restrict__ w2l, const float* __restrict__ b2,
    const float* __restrict__ lng, const float* __restrict__ lnb)
{
    __shared__ char buf[65536];
    // phase A: buf[0:32768) = Ahi [64][256] bf16 swizzled, buf[32768:65536) = Alo
    // phase C: buf reused as Z2 [64][256] f32
    const int tid  = threadIdx.x;
    const int lane = tid & 63;
    const int wv   = tid >> 6;
    const int cb   = lane & 15;   // n/m within fragment
    const int kg   = lane >> 4;   // k group
    const long row0 = (long)blockIdx.x * MT;

    // ---- load z tile, split hi/lo, store swizzled ----
    for (int rr = 0; rr < 16; rr++) {
        int row = wv * 16 + rr;
        long grow = row0 + row;
        float4 v = make_float4(0.f, 0.f, 0.f, 0.f);
        if (grow < N_NODES) v = *(const float4*)&z[grow * HD + lane * 4];
        ushort4 hi4, lo4;
        {
            unsigned short hb;
            hb = f2bf_rn(v.x); hi4.x = hb; lo4.x = f2bf_rn(v.x - bf2f(hb));
            hb = f2bf_rn(v.y); hi4.y = hb; lo4.y = f2bf_rn(v.y - bf2f(hb));
            hb = f2bf_rn(v.z); hi4.z = hb; lo4.z = f2bf_rn(v.z - bf2f(hb));
            hb = f2bf_rn(v.w); hi4.w = hb; lo4.w = f2bf_rn(v.w - bf2f(hb));
        }
        int byte = (row * 512 + lane * 8) ^ ((row & 7) << 4);
        *(ushort4*)(buf + byte)         = hi4;
        *(ushort4*)(buf + 32768 + byte) = lo4;
    }
    __syncthreads();

    f4_t acc[4][4];
    const f4_t zero4 = {0.f, 0.f, 0.f, 0.f};
    #pragma unroll
    for (int mi = 0; mi < 4; mi++)
        #pragma unroll
        for (int ni = 0; ni < 4; ni++) acc[mi][ni] = zero4;

    // ---- matmul1: t = z @ w1 (3 passes: Ahi*Bhi, Alo*Bhi, Ahi*Blo) ----
    #pragma unroll
    for (int pass = 0; pass < 3; pass++) {
        const char*  Abase = (pass == 1) ? (buf + 32768) : buf;
        const short* Bsrc  = (pass == 2) ? w1l : w1h;
        for (int kb = 0; kb < 8; kb++) {
            bf8_t a[4], b[4];
            #pragma unroll
            for (int mi = 0; mi < 4; mi++) {
                int row = mi * 16 + cb;
                int byte = (row * 512 + kb * 64 + kg * 16) ^ ((row & 7) << 4);
                a[mi] = *(const bf8_t*)(Abase + byte);
            }
            #pragma unroll
            for (int ni = 0; ni < 4; ni++) {
                int nb = wv * 4 + ni;
                b[ni] = *(const bf8_t*)&Bsrc[(size_t)(nb * 8 + kb) * 512 + lane * 8];
            }
            #pragma unroll
            for (int mi = 0; mi < 4; mi++)
                #pragma unroll
                for (int ni = 0; ni < 4; ni++)
                    acc[mi][ni] = __builtin_amdgcn_mfma_f32_16x16x32_bf16(a[mi], b[ni], acc[mi][ni], 0, 0, 0);
        }
    }
    __syncthreads();

    // ---- t = relu(. + b1), split hi/lo, store back into A buffers ----
    {
        float bias1[4];
        #pragma unroll
        for (int ni = 0; ni < 4; ni++) bias1[ni] = b1[wv * 64 + ni * 16 + cb];
        #pragma unroll
        for (int mi = 0; mi < 4; mi++) {
            #pragma unroll
            for (int ni = 0; ni < 4; ni++) {
                int colx2 = (wv * 64 + ni * 16 + cb) * 2;
                #pragma unroll
                for (int j = 0; j < 4; j++) {
                    float t = relu_f(acc[mi][ni][j] + bias1[ni]);
                    int row = mi * 16 + kg * 4 + j;
                    unsigned short hb = f2bf_rn(t);
                    unsigned short lb = f2bf_rn(t - bf2f(hb));
                    int byte = (row * 512 + colx2) ^ ((row & 7) << 4);
                    *(short*)(buf + byte)         = (short)hb;
                    *(short*)(buf + 32768 + byte) = (short)lb;
                }
            }
        }
    }
    __syncthreads();

    #pragma unroll
    for (int mi = 0; mi < 4; mi++)
        #pragma unroll
        for (int ni = 0; ni < 4; ni++) acc[mi][ni] = zero4;

    // ---- matmul2: z2 = t @ w2 ----
    #pragma unroll
    for (int pass = 0; pass < 3; pass++) {
        const char*  Abase = (pass == 1) ? (buf + 32768) : buf;
        const short* Bsrc  = (pass == 2) ? w2l : w2h;
        for (int kb = 0; kb < 8; kb++) {
            bf8_t a[4], b[4];
            #pragma unroll
            for (int mi = 0; mi < 4; mi++) {
                int row = mi * 16 + cb;
                int byte = (row * 512 + kb * 64 + kg * 16) ^ ((row & 7) << 4);
                a[mi] = *(const bf8_t*)(Abase + byte);
            }
            #pragma unroll
            for (int ni = 0; ni < 4; ni++) {
                int nb = wv * 4 + ni;
                b[ni] = *(const bf8_t*)&Bsrc[(size_t)(nb * 8 + kb) * 512 + lane * 8];
            }
            #pragma unroll
            for (int mi = 0; mi < 4; mi++)
                #pragma unroll
                for (int ni = 0; ni < 4; ni++)
                    acc[mi][ni] = __builtin_amdgcn_mfma_f32_16x16x32_bf16(a[mi], b[ni], acc[mi][ni], 0, 0, 0);
        }
    }
    __syncthreads();

    // ---- z2 + b2 -> LDS as f32 ----
    {
        float* Z2 = (float*)buf;
        float bias2[4];
        #pragma unroll
        for (int ni = 0; ni < 4; ni++) bias2[ni] = b2[wv * 64 + ni * 16 + cb];
        #pragma unroll
        for (int mi = 0; mi < 4; mi++) {
            #pragma unroll
            for (int ni = 0; ni < 4; ni++) {
                int colv = wv * 64 + ni * 16 + cb;
                #pragma unroll
                for (int j = 0; j < 4; j++) {
                    int row = mi * 16 + kg * 4 + j;
                    Z2[row * HD + colv] = acc[mi][ni][j] + bias2[ni];
                }
            }
        }
    }
    __syncthreads();

    // ---- LN + relu + residual ----
    {
        const float* Z2 = (const float*)buf;
        const float4 gv = *(const float4*)&lng[lane * 4];
        const float4 bv = *(const float4*)&lnb[lane * 4];
        for (int rr = 0; rr < 16; rr++) {
            int row = wv * 16 + rr;
            long grow = row0 + row;
            if (grow >= N_NODES) break;
            float4 v = *(const float4*)&Z2[row * HD + lane * 4];
            float s = v.x + v.y + v.z + v.w;
            float q = v.x * v.x + v.y * v.y + v.z * v.z + v.w * v.w;
            #pragma unroll
            for (int off = 32; off > 0; off >>= 1) {
                s += __shfl_xor(s, off, 64);
                q += __shfl_xor(q, off, 64);
            }
            float mu = s * (1.0f / 256.0f);
            float var = q * (1.0f / 256.0f) - mu * mu;
            float rstd = rsqrtf(var + LN_EPS);
            size_t gi = (size_t)grow * HD + lane * 4;
            float4 hv = *(float4*)&h[gi];
            hv.x += relu_f((v.x - mu) * rstd * gv.x + bv.x);
            hv.y += relu_f((v.y - mu) * rstd * gv.y + bv.y);
            hv.z += relu_f((v.z - mu) * rstd * gv.z + bv.z);
            hv.w += relu_f((v.w - mu) * rstd * gv.w + bv.w);
            *(float4*)&h[gi] = hv;
        }
    }
}

// ---------------- gate via split-bf16 MFMA: gate = relu(h@gw1+gb1)@gw2 + gb2 ----------------
__global__ __launch_bounds__(256, 2) void gate_mfma_kernel(
    const float* __restrict__ h,
    const short* __restrict__ g1h, const short* __restrict__ g1l, const float* __restrict__ gb1,
    const float* __restrict__ gw2, const float* __restrict__ gb2,
    float* __restrict__ gate)
{
    __shared__ char buf[65536];
    const int tid  = threadIdx.x;
    const int lane = tid & 63;
    const int wv   = tid >> 6;
    const int cb   = lane & 15;
    const int kg   = lane >> 4;
    const long row0 = (long)blockIdx.x * MT;

    for (int rr = 0; rr < 16; rr++) {
        int row = wv * 16 + rr;
        long grow = row0 + row;
        float4 v = make_float4(0.f, 0.f, 0.f, 0.f);
        if (grow < N_NODES) v = *(const float4*)&h[grow * HD + lane * 4];
        ushort4 hi4, lo4;
        {
            unsigned short hb;
            hb = f2bf_rn(v.x); hi4.x = hb; lo4.x = f2bf_rn(v.x - bf2f(hb));
            hb = f2bf_rn(v.y); hi4.y = hb; lo4.y = f2bf_rn(v.y - bf2f(hb));
            hb = f2bf_rn(v.z); hi4.z = hb; lo4.z = f2bf_rn(v.z - bf2f(hb));
            hb = f2bf_rn(v.w); hi4.w = hb; lo4.w = f2bf_rn(v.w - bf2f(hb));
        }
        int byte = (row * 512 + lane * 8) ^ ((row & 7) << 4);
        *(ushort4*)(buf + byte)         = hi4;
        *(ushort4*)(buf + 32768 + byte) = lo4;
    }
    __syncthreads();

    f4_t acc[4][2];
    const f4_t zero4 = {0.f, 0.f, 0.f, 0.f};
    #pragma unroll
    for (int mi = 0; mi < 4; mi++) { acc[mi][0] = zero4; acc[mi][1] = zero4; }

    #pragma unroll
    for (int pass = 0; pass < 3; pass++) {
        const char*  Abase = (pass == 1) ? (buf + 32768) : buf;
        const short* Bsrc  = (pass == 2) ? g1l : g1h;
        for (int kb = 0; kb < 8; kb++) {
            bf8_t a[4], b[2];
            #pragma unroll
            for (int mi = 0; mi < 4; mi++) {
                int row = mi * 16 + cb;
                int byte = (row * 512 + kb * 64 + kg * 16) ^ ((row & 7) << 4);
                a[mi] = *(const bf8_t*)(Abase + byte);
            }
            #pragma unroll
            for (int ni = 0; ni < 2; ni++) {
                int nb = wv * 2 + ni;
                b[ni] = *(const bf8_t*)&Bsrc[(size_t)(nb * 8 + kb) * 512 + lane * 8];
            }
            #pragma unroll
            for (int mi = 0; mi < 4; mi++)
                #pragma unroll
                for (int ni = 0; ni < 2; ni++)
                    acc[mi][ni] = __builtin_amdgcn_mfma_f32_16x16x32_bf16(a[mi], b[ni], acc[mi][ni], 0, 0, 0);
        }
    }
    __syncthreads();

    // gate1 = relu(. + gb1) -> LDS f32 [64][128]
    {
        float* G1 = (float*)buf;
        float bias1[2];
        bias1[0] = gb1[wv * 32 + cb];
        bias1[1] = gb1[wv * 32 + 16 + cb];
        #pragma unroll
        for (int mi = 0; mi < 4; mi++) {
            #pragma unroll
            for (int ni = 0; ni < 2; ni++) {
                int colv = wv * 32 + ni * 16 + cb;
                #pragma unroll
                for (int j = 0; j < 4; j++) {
                    int row = mi * 16 + kg * 4 + j;
                    G1[row * PHD + colv] = relu_f(acc[mi][ni][j] + bias1[ni]);
                }
            }
        }
    }
    __syncthreads();

    // stage 2: dot with gw2 over 128
    {
        const float* G1 = (const float*)buf;
        float2 wv2 = *(const float2*)&gw2[lane * 2];
        float b2v = gb2[0];
        for (int rr = 0; rr < 16; rr++) {
            int row = wv * 16 + rr;
            long grow = row0 + row;
            if (grow >= N_NODES) break;
            float2 t2 = *(const float2*)&G1[row * PHD + lane * 2];
            float p = t2.x * wv2.x + t2.y * wv2.y;
            #pragma unroll
            for (int off = 32; off > 0; off >>= 1) p += __shfl_xor(p, off, 64);
            if (lane == 0) gate[grow] = p + b2v;
        }
    }
}

// ---------------- graph offsets ----------------
__global__ void goff_kernel(const int* __restrict__ batch, int* __restrict__ goff, int n)
{
    int t = threadIdx.x;
    if (t > NG) return;
    int lo = 0, hi = n;
    while (lo < hi) {
        int mid = (lo + hi) >> 1;
        if (batch[mid] < t) lo = mid + 1; else hi = mid;
    }
    goff[t] = lo;
}

// ---------------- softmax-weighted pooling ----------------
__global__ __launch_bounds__(256) void pool_kernel(
    const float* __restrict__ h, const float* __restrict__ gate,
    const int* __restrict__ goff, float* __restrict__ a_scratch,
    float* __restrict__ pooled)
{
    __shared__ float red[256];
    __shared__ float m_sh, s_sh;
    int g = blockIdx.x, tid = threadIdx.x;
    int beg = goff[g], end = goff[g + 1];
    if (beg >= end) { pooled[(size_t)g * HD + tid] = 0.0f; return; }

    float lm = -3.4e38f;
    for (int i = beg + tid; i < end; i += 256) lm = fmaxf(lm, gate[i]);
    red[tid] = lm; __syncthreads();
    for (int off = 128; off > 0; off >>= 1) {
        if (tid < off) red[tid] = fmaxf(red[tid], red[tid + off]);
        __syncthreads();
    }
    if (tid == 0) m_sh = red[0];
    __syncthreads();
    float m = m_sh;

    float ls = 0.0f;
    for (int i = beg + tid; i < end; i += 256) {
        float a = expf(gate[i] - m);
        a_scratch[i] = a;
        ls += a;
    }
    __syncthreads();
    red[tid] = ls; __syncthreads();
    for (int off = 128; off > 0; off >>= 1) {
        if (tid < off) red[tid] += red[tid + off];
        __syncthreads();
    }
    if (tid == 0) s_sh = red[0];
    __syncthreads();
    float inv_s = 1.0f / s_sh;

    float acc = 0.0f;
    for (int i = beg; i < end; i++) {
        acc += a_scratch[i] * h[(size_t)i * HD + tid];
    }
    pooled[(size_t)g * HD + tid] = acc * inv_s;
}

// ---------------- classifier ----------------
__global__ __launch_bounds__(128) void cls_kernel(
    const float* __restrict__ pooled, const float* __restrict__ gf,
    const float* __restrict__ w1, const float* __restrict__ b1,
    const float* __restrict__ w2, const float* __restrict__ b2,
    float* __restrict__ out)
{
    __shared__ float r0[128], r1[128];
    int g = blockIdx.x, c = threadIdx.x;
    float acc = b1[c];
    const float* pr = pooled + (size_t)g * HD;
    for (int k = 0; k < HD; k++) acc += pr[k] * w1[k * PHD + c];
    const float* gr = gf + g * GFD;
    for (int k = 0; k < GFD; k++) acc += gr[k] * w1[(HD + k) * PHD + c];
    float t = relu_f(acc);
    r0[c] = t * w2[c * 2 + 0];
    r1[c] = t * w2[c * 2 + 1];
    __syncthreads();
    for (int off = 64; off > 0; off >>= 1) {
        if (c < off) { r0[c] += r0[c + off]; r1[c] += r1[c + off]; }
        __syncthreads();
    }
    if (c == 0) {
        out[g * 2 + 0] = r0[0] + b2[0];
        out[g * 2 + 1] = r1[0] + b2[1];
    }
}

extern "C" void kernel_launch(void* const* d_in, const int* in_sizes, int n_in,
                              void* d_out, int out_size, void* d_ws, size_t ws_size,
                              hipStream_t stream)
{
    const float* x    = (const float*)d_in[0];
    const int*   ei   = (const int*)d_in[1];
    const int*   bat  = (const int*)d_in[2];
    const float* gf   = (const float*)d_in[3];
    const float* emb  = (const float*)d_in[4];
    const float* l0w1 = (const float*)d_in[5];
    const float* l0b1 = (const float*)d_in[6];
    const float* l0w2 = (const float*)d_in[7];
    const float* l0b2 = (const float*)d_in[8];
    const float* ln0g = (const float*)d_in[9];
    const float* ln0b = (const float*)d_in[10];
    const float* l1w1 = (const float*)d_in[11];
    const float* l1b1 = (const float*)d_in[12];
    const float* l1w2 = (const float*)d_in[13];
    const float* l1b2 = (const float*)d_in[14];
    const float* ln1g = (const float*)d_in[15];
    const float* ln1b = (const float*)d_in[16];
    const float* gw1  = (const float*)d_in[17];
    const float* gb1  = (const float*)d_in[18];
    const float* gw2  = (const float*)d_in[19];
    const float* gb2  = (const float*)d_in[20];
    const float* cw1  = (const float*)d_in[21];
    const float* cb1  = (const float*)d_in[22];
    const float* cw2  = (const float*)d_in[23];
    const float* cb2  = (const float*)d_in[24];

    char* ws = (char*)d_ws;
    size_t off = 0;
    auto alloc = [&](size_t bytes) {
        void* p = ws + off;
        off += (bytes + 255) & ~(size_t)255;
        return p;
    };
    float* h      = (float*)alloc((size_t)N_NODES * HD * 4);
    float* z      = (float*)alloc((size_t)N_NODES * HD * 4);
    float* gate   = (float*)alloc((size_t)N_NODES * 4);
    int*   rowptr = (int*)alloc((size_t)(N_NODES + 1) * 4);
    int*   cursor = (int*)alloc((size_t)N_NODES * 4);
    int*   col    = (int*)alloc((size_t)N_EDGES * 4);
    int*   goff   = (int*)alloc((NG + 1) * 4);
    float* pooled = (float*)alloc((size_t)NG * HD * 4);
    // packed weights (bf16 hi/lo in MFMA B-fragment layout)
    short* p_l0w1h = (short*)alloc((size_t)HD * HD * 2);
    short* p_l0w1l = (short*)alloc((size_t)HD * HD * 2);
    short* p_l0w2h = (short*)alloc((size_t)HD * HD * 2);
    short* p_l0w2l = (short*)alloc((size_t)HD * HD * 2);
    short* p_l1w1h = (short*)alloc((size_t)HD * HD * 2);
    short* p_l1w1l = (short*)alloc((size_t)HD * HD * 2);
    short* p_l1w2h = (short*)alloc((size_t)HD * HD * 2);
    short* p_l1w2l = (short*)alloc((size_t)HD * HD * 2);
    short* p_gw1h  = (short*)alloc((size_t)HD * PHD * 2);
    short* p_gw1l  = (short*)alloc((size_t)HD * PHD * 2);

    const int* src = ei;
    const int* dst = ei + N_EDGES;

    build_h_kernel<<<N_NODES, 256, 0, stream>>>(x, emb, h);

    hipMemsetAsync(cursor, 0, (size_t)N_NODES * 4, stream);
    count_deg_kernel<<<(N_EDGES + 255) / 256, 256, 0, stream>>>(dst, cursor, N_EDGES);
    scan_kernel<<<1, 1024, 0, stream>>>(cursor, rowptr, N_NODES);
    fill_csr_kernel<<<(N_EDGES + 255) / 256, 256, 0, stream>>>(src, dst, cursor, col, N_EDGES);

    pack_w_kernel<<<32, 256, 0, stream>>>(l0w1, p_l0w1h, p_l0w1l, HD, HD);
    pack_w_kernel<<<32, 256, 0, stream>>>(l0w2, p_l0w2h, p_l0w2l, HD, HD);
    pack_w_kernel<<<32, 256, 0, stream>>>(l1w1, p_l1w1h, p_l1w1l, HD, HD);
    pack_w_kernel<<<32, 256, 0, stream>>>(l1w2, p_l1w2h, p_l1w2l, HD, HD);
    pack_w_kernel<<<16, 256, 0, stream>>>(gw1, p_gw1h, p_gw1l, HD, PHD);

    const int mlp_grid = (N_NODES + MT - 1) / MT;

    // GIN block 0
    aggregate_kernel<<<N_NODES / 4, 256, 0, stream>>>(h, rowptr, col, z, N_NODES);
    mlp_mfma_kernel<<<mlp_grid, 256, 0, stream>>>(h, z, p_l0w1h, p_l0w1l, l0b1,
                                                  p_l0w2h, p_l0w2l, l0b2, ln0g, ln0b);
    // GIN block 1
    aggregate_kernel<<<N_NODES / 4, 256, 0, stream>>>(h, rowptr, col, z, N_NODES);
    mlp_mfma_kernel<<<mlp_grid, 256, 0, stream>>>(h, z, p_l1w1h, p_l1w1l, l1b1,
                                                  p_l1w2h, p_l1w2l, l1b2, ln1g, ln1b);

    gate_mfma_kernel<<<mlp_grid, 256, 0, stream>>>(h, p_gw1h, p_gw1l, gb1, gw2, gb2, gate);
    goff_kernel<<<1, 256, 0, stream>>>(bat, goff, N_NODES);
    pool_kernel<<<NG, 256, 0, stream>>>(h, gate, goff, z, pooled);
    cls_kernel<<<NG, 128, 0, stream>>>(pooled, gf, cw1, cb1, cw2, cb2, (float*)d_out);
}

// Round 6
// 1721.146 us; speedup vs baseline: 1.2809x; 1.0978x over previous
//
// GINCombined r5 resubmit (r3/r4/r5 infra failures: UnresponsiveContainer pre-push; kernel unchanged from r3)
#include <hip/hip_runtime.h>
#include <math.h>

#define N_NODES 100000
#define N_EDGES 1600000
#define NG      128
#define HD      256
#define PHD     128
#define GFD     32
#define XW      241
#define LN_EPS  1e-5f

typedef __attribute__((ext_vector_type(8))) short bf8_t;  // 8 bf16 (4 VGPR)
typedef __attribute__((ext_vector_type(4))) float f4_t;   // 4 f32 acc

static __device__ __forceinline__ float relu_f(float x){ return fmaxf(x, 0.0f); }

static __device__ __forceinline__ unsigned short f2bf_rn(float v) {
    unsigned int u = __float_as_uint(v);
    unsigned int r = (u + 0x7fffu + ((u >> 16) & 1u)) >> 16;
    return (unsigned short)r;
}
static __device__ __forceinline__ float bf2f(unsigned short h) {
    return __uint_as_float((unsigned int)h << 16);
}

// ---------------- h build ----------------
__global__ void build_h_kernel(const float* __restrict__ x, const float* __restrict__ emb,
                               float* __restrict__ h)
{
    int node = blockIdx.x;
    int tid  = threadIdx.x;
    const float* xr = x + (size_t)node * XW;
    float v;
    if (tid < 240) {
        v = xr[1 + tid];
    } else {
        int t = (int)xr[0];
        v = emb[t * 16 + (tid - 240)];
    }
    h[(size_t)node * HD + tid] = v;
}

// ---------------- CSR build ----------------
__global__ void count_deg_kernel(const int* __restrict__ dst, int* __restrict__ cnt, int e)
{
    int i = blockIdx.x * blockDim.x + threadIdx.x;
    if (i < e) atomicAdd(&cnt[dst[i]], 1);
}

__global__ void scan_kernel(int* __restrict__ cursor, int* __restrict__ rowptr, int n)
{
    __shared__ int tot[1024];
    int tid = threadIdx.x;
    int chunk = (n + 1023) >> 10;
    int beg = tid * chunk; if (beg > n) beg = n;
    int end = beg + chunk; if (end > n) end = n;
    int s = 0;
    for (int i = beg; i < end; i++) s += cursor[i];
    tot[tid] = s;
    __syncthreads();
    for (int off = 1; off < 1024; off <<= 1) {
        int v = tot[tid];
        int add = (tid >= off) ? tot[tid - off] : 0;
        __syncthreads();
        tot[tid] = v + add;
        __syncthreads();
    }
    int run = (tid > 0) ? tot[tid - 1] : 0;
    for (int i = beg; i < end; i++) {
        int d = cursor[i];
        rowptr[i] = run;
        cursor[i] = run;
        run += d;
    }
    if (tid == 1023) rowptr[n] = tot[1023];
}

__global__ void fill_csr_kernel(const int* __restrict__ src, const int* __restrict__ dst,
                                int* __restrict__ cursor, int* __restrict__ col, int e)
{
    int i = blockIdx.x * blockDim.x + threadIdx.x;
    if (i < e) {
        int p = atomicAdd(&cursor[dst[i]], 1);
        col[p] = src[i];
    }
}

// ---------------- aggregate: z = h + sum_neighbors h (4-way unrolled) ----------------
__global__ __launch_bounds__(256) void aggregate_kernel(
    const float* __restrict__ h, const int* __restrict__ rowptr,
    const int* __restrict__ col, float* __restrict__ z, int n)
{
    int node = blockIdx.x * 4 + (threadIdx.x >> 6);
    int lane = threadIdx.x & 63;
    if (node >= n) return;
    size_t base = (size_t)node * HD + lane * 4;
    const int l4 = lane * 4;
    float4 a0 = *(const float4*)&h[base];
    float4 a1 = make_float4(0,0,0,0), a2 = make_float4(0,0,0,0), a3 = make_float4(0,0,0,0);
    int e = rowptr[node], e1 = rowptr[node + 1];
    for (; e + 4 <= e1; e += 4) {
        int s0 = col[e], s1 = col[e+1], s2 = col[e+2], s3 = col[e+3];
        float4 v0 = *(const float4*)&h[(size_t)s0 * HD + l4];
        float4 v1 = *(const float4*)&h[(size_t)s1 * HD + l4];
        float4 v2 = *(const float4*)&h[(size_t)s2 * HD + l4];
        float4 v3 = *(const float4*)&h[(size_t)s3 * HD + l4];
        a0.x += v0.x; a0.y += v0.y; a0.z += v0.z; a0.w += v0.w;
        a1.x += v1.x; a1.y += v1.y; a1.z += v1.z; a1.w += v1.w;
        a2.x += v2.x; a2.y += v2.y; a2.z += v2.z; a2.w += v2.w;
        a3.x += v3.x; a3.y += v3.y; a3.z += v3.z; a3.w += v3.w;
    }
    for (; e < e1; e++) {
        int s = col[e];
        float4 v = *(const float4*)&h[(size_t)s * HD + l4];
        a0.x += v.x; a0.y += v.y; a0.z += v.z; a0.w += v.w;
    }
    a0.x += a1.x + a2.x + a3.x;
    a0.y += a1.y + a2.y + a3.y;
    a0.z += a1.z + a2.z + a3.z;
    a0.w += a1.w + a2.w + a3.w;
    *(float4*)&z[base] = a0;
}

// ---------------- weight packing into B-fragment layout (hi/lo bf16) ----------------
__global__ void pack_w_kernel(const float* __restrict__ w, short* __restrict__ hi,
                              short* __restrict__ lo, int K, int N)
{
    int t = blockIdx.x * blockDim.x + threadIdx.x;
    int lane = t & 63;
    int f = t >> 6;
    int KB = K >> 5;
    int NB = N >> 4;
    if (f >= KB * NB) return;
    int nb = f / KB, kb = f % KB;
    int n = nb * 16 + (lane & 15);
    int k0 = kb * 32 + (lane >> 4) * 8;
    size_t o = (size_t)f * 512 + lane * 8;
    #pragma unroll
    for (int j = 0; j < 8; j++) {
        float v = w[(size_t)(k0 + j) * N + n];
        unsigned short hb = f2bf_rn(v);
        float hf = bf2f(hb);
        unsigned short lb = f2bf_rn(v - hf);
        hi[o + j] = (short)hb;
        lo[o + j] = (short)lb;
    }
}

// 128-row split-bf16 matmul block: acc += (Ahi+Alo)@Bh + Ahi@Bl
// A hi at buf[0:64K), lo at buf[64K:128K), swizzled; B in packed fragment layout.
static __device__ __forceinline__ void mm128(
    f4_t (&acc)[4][4], const char* buf,
    const short* __restrict__ Bh, const short* __restrict__ Bl,
    int wr, int wc, int cb, int kg, int lane)
{
    bf8_t bcur[4], bnxt[4];
    // ---- pass A: (Ahi + Alo) * Bh ----
    #pragma unroll
    for (int ni = 0; ni < 4; ni++)
        bcur[ni] = *(const bf8_t*)&Bh[((size_t)((wc*4+ni)*8 + 0))*512 + lane*8];
    for (int kb = 0; kb < 8; kb++) {
        if (kb < 7) {
            #pragma unroll
            for (int ni = 0; ni < 4; ni++)
                bnxt[ni] = *(const bf8_t*)&Bh[((size_t)((wc*4+ni)*8 + kb+1))*512 + lane*8];
        }
        bf8_t ahi[4], alo[4];
        #pragma unroll
        for (int mi = 0; mi < 4; mi++) {
            int row = wr*64 + mi*16 + cb;
            int byte = (row*512 + kb*64 + kg*16) ^ ((row & 7) << 4);
            ahi[mi] = *(const bf8_t*)(buf + byte);
            alo[mi] = *(const bf8_t*)(buf + 65536 + byte);
        }
        #pragma unroll
        for (int mi = 0; mi < 4; mi++)
            #pragma unroll
            for (int ni = 0; ni < 4; ni++)
                acc[mi][ni] = __builtin_amdgcn_mfma_f32_16x16x32_bf16(ahi[mi], bcur[ni], acc[mi][ni], 0, 0, 0);
        #pragma unroll
        for (int mi = 0; mi < 4; mi++)
            #pragma unroll
            for (int ni = 0; ni < 4; ni++)
                acc[mi][ni] = __builtin_amdgcn_mfma_f32_16x16x32_bf16(alo[mi], bcur[ni], acc[mi][ni], 0, 0, 0);
        #pragma unroll
        for (int ni = 0; ni < 4; ni++) bcur[ni] = bnxt[ni];
    }
    // ---- pass B: Ahi * Bl ----
    #pragma unroll
    for (int ni = 0; ni < 4; ni++)
        bcur[ni] = *(const bf8_t*)&Bl[((size_t)((wc*4+ni)*8 + 0))*512 + lane*8];
    for (int kb = 0; kb < 8; kb++) {
        if (kb < 7) {
            #pragma unroll
            for (int ni = 0; ni < 4; ni++)
                bnxt[ni] = *(const bf8_t*)&Bl[((size_t)((wc*4+ni)*8 + kb+1))*512 + lane*8];
        }
        bf8_t ahi[4];
        #pragma unroll
        for (int mi = 0; mi < 4; mi++) {
            int row = wr*64 + mi*16 + cb;
            int byte = (row*512 + kb*64 + kg*16) ^ ((row & 7) << 4);
            ahi[mi] = *(const bf8_t*)(buf + byte);
        }
        #pragma unroll
        for (int mi = 0; mi < 4; mi++)
            #pragma unroll
            for (int ni = 0; ni < 4; ni++)
                acc[mi][ni] = __builtin_amdgcn_mfma_f32_16x16x32_bf16(ahi[mi], bcur[ni], acc[mi][ni], 0, 0, 0);
        #pragma unroll
        for (int ni = 0; ni < 4; ni++) bcur[ni] = bnxt[ni];
    }
}

// ---------------- fused MLP + LN + residual (128 rows/block, 8 waves, 128KB LDS) ----------------
__global__ __launch_bounds__(512, 2) void mlp_mfma_kernel(
    float* __restrict__ h, const float* __restrict__ z,
    const short* __restrict__ w1h, const short* __restrict__ w1l, const float* __restrict__ b1,
    const short* __restrict__ w2h, const short* __restrict__ w2l, const float* __restrict__ b2,
    const float* __restrict__ lng, const float* __restrict__ lnb)
{
    extern __shared__ char buf[];   // 131072 bytes
    const int tid  = threadIdx.x;
    const int lane = tid & 63;
    const int wv   = tid >> 6;      // 0..7
    const int wr   = wv >> 2;       // 0..1
    const int wc   = wv & 3;        // 0..3
    const int cb   = lane & 15;
    const int kg   = lane >> 4;
    const long row0 = (long)blockIdx.x * 128;

    // ---- stage z tile [128][256]: split hi/lo, swizzled ----
    for (int rr = 0; rr < 16; rr++) {
        int row = wv * 16 + rr;
        long grow = row0 + row;
        float4 v = make_float4(0.f, 0.f, 0.f, 0.f);
        if (grow < N_NODES) v = *(const float4*)&z[grow * HD + lane * 4];
        ushort4 hi4, lo4;
        unsigned short hb;
        hb = f2bf_rn(v.x); hi4.x = hb; lo4.x = f2bf_rn(v.x - bf2f(hb));
        hb = f2bf_rn(v.y); hi4.y = hb; lo4.y = f2bf_rn(v.y - bf2f(hb));
        hb = f2bf_rn(v.z); hi4.z = hb; lo4.z = f2bf_rn(v.z - bf2f(hb));
        hb = f2bf_rn(v.w); hi4.w = hb; lo4.w = f2bf_rn(v.w - bf2f(hb));
        int byte = (row * 512 + lane * 8) ^ ((row & 7) << 4);
        *(ushort4*)(buf + byte)         = hi4;
        *(ushort4*)(buf + 65536 + byte) = lo4;
    }
    __syncthreads();

    f4_t acc[4][4];
    const f4_t zero4 = {0.f, 0.f, 0.f, 0.f};
    #pragma unroll
    for (int mi = 0; mi < 4; mi++)
        #pragma unroll
        for (int ni = 0; ni < 4; ni++) acc[mi][ni] = zero4;

    mm128(acc, buf, w1h, w1l, wr, wc, cb, kg, lane);
    __syncthreads();

    // ---- t = relu(acc + b1) -> hi/lo swizzled back into buf ----
    {
        float bias1[4];
        #pragma unroll
        for (int ni = 0; ni < 4; ni++) bias1[ni] = b1[wc * 64 + ni * 16 + cb];
        #pragma unroll
        for (int mi = 0; mi < 4; mi++) {
            #pragma unroll
            for (int ni = 0; ni < 4; ni++) {
                int colx2 = (wc * 64 + ni * 16 + cb) * 2;
                #pragma unroll
                for (int j = 0; j < 4; j++) {
                    float t = relu_f(acc[mi][ni][j] + bias1[ni]);
                    int row = wr * 64 + mi * 16 + kg * 4 + j;
                    unsigned short hb = f2bf_rn(t);
                    unsigned short lb = f2bf_rn(t - bf2f(hb));
                    int byte = (row * 512 + colx2) ^ ((row & 7) << 4);
                    *(short*)(buf + byte)         = (short)hb;
                    *(short*)(buf + 65536 + byte) = (short)lb;
                }
            }
        }
    }
    __syncthreads();

    #pragma unroll
    for (int mi = 0; mi < 4; mi++)
        #pragma unroll
        for (int ni = 0; ni < 4; ni++) acc[mi][ni] = zero4;

    mm128(acc, buf, w2h, w2l, wr, wc, cb, kg, lane);
    __syncthreads();

    // ---- z2 = acc + b2 -> f32 [128][256] over whole buf (64B-chunk swizzle) ----
    {
        float bias2[4];
        #pragma unroll
        for (int ni = 0; ni < 4; ni++) bias2[ni] = b2[wc * 64 + ni * 16 + cb];
        #pragma unroll
        for (int mi = 0; mi < 4; mi++) {
            #pragma unroll
            for (int ni = 0; ni < 4; ni++) {
                int col = wc * 64 + ni * 16 + cb;
                #pragma unroll
                for (int j = 0; j < 4; j++) {
                    int row = wr * 64 + mi * 16 + kg * 4 + j;
                    int byte = (row * 1024 + col * 4) ^ (((row >> 2) & 3) << 6);
                    *(float*)(buf + byte) = acc[mi][ni][j] + bias2[ni];
                }
            }
        }
    }
    __syncthreads();

    // ---- LN + relu + residual ----
    {
        const float4 gv = *(const float4*)&lng[lane * 4];
        const float4 bv = *(const float4*)&lnb[lane * 4];
        for (int rr = 0; rr < 16; rr++) {
            int row = wv * 16 + rr;
            long grow = row0 + row;
            if (grow >= N_NODES) break;
            int byte = (row * 1024 + lane * 16) ^ (((row >> 2) & 3) << 6);
            float4 v = *(const float4*)(buf + byte);
            float s = v.x + v.y + v.z + v.w;
            float q = v.x * v.x + v.y * v.y + v.z * v.z + v.w * v.w;
            #pragma unroll
            for (int off = 32; off > 0; off >>= 1) {
                s += __shfl_xor(s, off, 64);
                q += __shfl_xor(q, off, 64);
            }
            float mu = s * (1.0f / 256.0f);
            float var = q * (1.0f / 256.0f) - mu * mu;
            float rstd = rsqrtf(var + LN_EPS);
            size_t gi = (size_t)grow * HD + lane * 4;
            float4 hv = *(float4*)&h[gi];
            hv.x += relu_f((v.x - mu) * rstd * gv.x + bv.x);
            hv.y += relu_f((v.y - mu) * rstd * gv.y + bv.y);
            hv.z += relu_f((v.z - mu) * rstd * gv.z + bv.z);
            hv.w += relu_f((v.w - mu) * rstd * gv.w + bv.w);
            *(float4*)&h[gi] = hv;
        }
    }
}

// ---------------- gate via split-bf16 MFMA (64 rows/block) ----------------
__global__ __launch_bounds__(256, 2) void gate_mfma_kernel(
    const float* __restrict__ h,
    const short* __restrict__ g1h, const short* __restrict__ g1l, const float* __restrict__ gb1,
    const float* __restrict__ gw2, const float* __restrict__ gb2,
    float* __restrict__ gate)
{
    __shared__ char buf[65536];
    const int tid  = threadIdx.x;
    const int lane = tid & 63;
    const int wv   = tid >> 6;
    const int cb   = lane & 15;
    const int kg   = lane >> 4;
    const long row0 = (long)blockIdx.x * 64;

    for (int rr = 0; rr < 16; rr++) {
        int row = wv * 16 + rr;
        long grow = row0 + row;
        float4 v = make_float4(0.f, 0.f, 0.f, 0.f);
        if (grow < N_NODES) v = *(const float4*)&h[grow * HD + lane * 4];
        ushort4 hi4, lo4;
        unsigned short hb;
        hb = f2bf_rn(v.x); hi4.x = hb; lo4.x = f2bf_rn(v.x - bf2f(hb));
        hb = f2bf_rn(v.y); hi4.y = hb; lo4.y = f2bf_rn(v.y - bf2f(hb));
        hb = f2bf_rn(v.z); hi4.z = hb; lo4.z = f2bf_rn(v.z - bf2f(hb));
        hb = f2bf_rn(v.w); hi4.w = hb; lo4.w = f2bf_rn(v.w - bf2f(hb));
        int byte = (row * 512 + lane * 8) ^ ((row & 7) << 4);
        *(ushort4*)(buf + byte)         = hi4;
        *(ushort4*)(buf + 32768 + byte) = lo4;
    }
    __syncthreads();

    f4_t acc[4][2];
    const f4_t zero4 = {0.f, 0.f, 0.f, 0.f};
    #pragma unroll
    for (int mi = 0; mi < 4; mi++) { acc[mi][0] = zero4; acc[mi][1] = zero4; }

    #pragma unroll
    for (int pass = 0; pass < 3; pass++) {
        const char*  Abase = (pass == 1) ? (buf + 32768) : buf;
        const short* Bsrc  = (pass == 2) ? g1l : g1h;
        for (int kb = 0; kb < 8; kb++) {
            bf8_t a[4], b[2];
            #pragma unroll
            for (int mi = 0; mi < 4; mi++) {
                int row = mi * 16 + cb;
                int byte = (row * 512 + kb * 64 + kg * 16) ^ ((row & 7) << 4);
                a[mi] = *(const bf8_t*)(Abase + byte);
            }
            #pragma unroll
            for (int ni = 0; ni < 2; ni++) {
                int nb = wv * 2 + ni;
                b[ni] = *(const bf8_t*)&Bsrc[(size_t)(nb * 8 + kb) * 512 + lane * 8];
            }
            #pragma unroll
            for (int mi = 0; mi < 4; mi++)
                #pragma unroll
                for (int ni = 0; ni < 2; ni++)
                    acc[mi][ni] = __builtin_amdgcn_mfma_f32_16x16x32_bf16(a[mi], b[ni], acc[mi][ni], 0, 0, 0);
        }
    }
    __syncthreads();

    {
        float* G1 = (float*)buf;
        float bias1[2];
        bias1[0] = gb1[wv * 32 + cb];
        bias1[1] = gb1[wv * 32 + 16 + cb];
        #pragma unroll
        for (int mi = 0; mi < 4; mi++) {
            #pragma unroll
            for (int ni = 0; ni < 2; ni++) {
                int colv = wv * 32 + ni * 16 + cb;
                #pragma unroll
                for (int j = 0; j < 4; j++) {
                    int row = mi * 16 + kg * 4 + j;
                    G1[row * PHD + colv] = relu_f(acc[mi][ni][j] + bias1[ni]);
                }
            }
        }
    }
    __syncthreads();

    {
        const float* G1 = (const float*)buf;
        float2 wv2 = *(const float2*)&gw2[lane * 2];
        float b2v = gb2[0];
        for (int rr = 0; rr < 16; rr++) {
            int row = wv * 16 + rr;
            long grow = row0 + row;
            if (grow >= N_NODES) break;
            float2 t2 = *(const float2*)&G1[row * PHD + lane * 2];
            float p = t2.x * wv2.x + t2.y * wv2.y;
            #pragma unroll
            for (int off = 32; off > 0; off >>= 1) p += __shfl_xor(p, off, 64);
            if (lane == 0) gate[grow] = p + b2v;
        }
    }
}

// ---------------- graph offsets ----------------
__global__ void goff_kernel(const int* __restrict__ batch, int* __restrict__ goff, int n)
{
    int t = threadIdx.x;
    if (t > NG) return;
    int lo = 0, hi = n;
    while (lo < hi) {
        int mid = (lo + hi) >> 1;
        if (batch[mid] < t) lo = mid + 1; else hi = mid;
    }
    goff[t] = lo;
}

// ---------------- softmax-weighted pooling ----------------
__global__ __launch_bounds__(256) void pool_kernel(
    const float* __restrict__ h, const float* __restrict__ gate,
    const int* __restrict__ goff, float* __restrict__ a_scratch,
    float* __restrict__ pooled)
{
    __shared__ float red[256];
    __shared__ float m_sh, s_sh;
    int g = blockIdx.x, tid = threadIdx.x;
    int beg = goff[g], end = goff[g + 1];
    if (beg >= end) { pooled[(size_t)g * HD + tid] = 0.0f; return; }

    float lm = -3.4e38f;
    for (int i = beg + tid; i < end; i += 256) lm = fmaxf(lm, gate[i]);
    red[tid] = lm; __syncthreads();
    for (int off = 128; off > 0; off >>= 1) {
        if (tid < off) red[tid] = fmaxf(red[tid], red[tid + off]);
        __syncthreads();
    }
    if (tid == 0) m_sh = red[0];
    __syncthreads();
    float m = m_sh;

    float ls = 0.0f;
    for (int i = beg + tid; i < end; i += 256) {
        float a = expf(gate[i] - m);
        a_scratch[i] = a;
        ls += a;
    }
    __syncthreads();
    red[tid] = ls; __syncthreads();
    for (int off = 128; off > 0; off >>= 1) {
        if (tid < off) red[tid] += red[tid + off];
        __syncthreads();
    }
    if (tid == 0) s_sh = red[0];
    __syncthreads();
    float inv_s = 1.0f / s_sh;

    float acc = 0.0f;
    for (int i = beg; i < end; i++) {
        acc += a_scratch[i] * h[(size_t)i * HD + tid];
    }
    pooled[(size_t)g * HD + tid] = acc * inv_s;
}

// ---------------- classifier ----------------
__global__ __launch_bounds__(128) void cls_kernel(
    const float* __restrict__ pooled, const float* __restrict__ gf,
    const float* __restrict__ w1, const float* __restrict__ b1,
    const float* __restrict__ w2, const float* __restrict__ b2,
    float* __restrict__ out)
{
    __shared__ float r0[128], r1[128];
    int g = blockIdx.x, c = threadIdx.x;
    float acc = b1[c];
    const float* pr = pooled + (size_t)g * HD;
    for (int k = 0; k < HD; k++) acc += pr[k] * w1[k * PHD + c];
    const float* gr = gf + g * GFD;
    for (int k = 0; k < GFD; k++) acc += gr[k] * w1[(HD + k) * PHD + c];
    float t = relu_f(acc);
    r0[c] = t * w2[c * 2 + 0];
    r1[c] = t * w2[c * 2 + 1];
    __syncthreads();
    for (int off = 64; off > 0; off >>= 1) {
        if (c < off) { r0[c] += r0[c + off]; r1[c] += r1[c + off]; }
        __syncthreads();
    }
    if (c == 0) {
        out[g * 2 + 0] = r0[0] + b2[0];
        out[g * 2 + 1] = r1[0] + b2[1];
    }
}

extern "C" void kernel_launch(void* const* d_in, const int* in_sizes, int n_in,
                              void* d_out, int out_size, void* d_ws, size_t ws_size,
                              hipStream_t stream)
{
    const float* x    = (const float*)d_in[0];
    const int*   ei   = (const int*)d_in[1];
    const int*   bat  = (const int*)d_in[2];
    const float* gf   = (const float*)d_in[3];
    const float* emb  = (const float*)d_in[4];
    const float* l0w1 = (const float*)d_in[5];
    const float* l0b1 = (const float*)d_in[6];
    const float* l0w2 = (const float*)d_in[7];
    const float* l0b2 = (const float*)d_in[8];
    const float* ln0g = (const float*)d_in[9];
    const float* ln0b = (const float*)d_in[10];
    const float* l1w1 = (const float*)d_in[11];
    const float* l1b1 = (const float*)d_in[12];
    const float* l1w2 = (const float*)d_in[13];
    const float* l1b2 = (const float*)d_in[14];
    const float* ln1g = (const float*)d_in[15];
    const float* ln1b = (const float*)d_in[16];
    const float* gw1  = (const float*)d_in[17];
    const float* gb1  = (const float*)d_in[18];
    const float* gw2  = (const float*)d_in[19];
    const float* gb2  = (const float*)d_in[20];
    const float* cw1  = (const float*)d_in[21];
    const float* cb1  = (const float*)d_in[22];
    const float* cw2  = (const float*)d_in[23];
    const float* cb2  = (const float*)d_in[24];

    char* ws = (char*)d_ws;
    size_t off = 0;
    auto alloc = [&](size_t bytes) {
        void* p = ws + off;
        off += (bytes + 255) & ~(size_t)255;
        return p;
    };
    float* h      = (float*)alloc((size_t)N_NODES * HD * 4);
    float* z      = (float*)alloc((size_t)N_NODES * HD * 4);
    float* gate   = (float*)alloc((size_t)N_NODES * 4);
    int*   rowptr = (int*)alloc((size_t)(N_NODES + 1) * 4);
    int*   cursor = (int*)alloc((size_t)N_NODES * 4);
    int*   col    = (int*)alloc((size_t)N_EDGES * 4);
    int*   goff   = (int*)alloc((NG + 1) * 4);
    float* pooled = (float*)alloc((size_t)NG * HD * 4);
    short* p_l0w1h = (short*)alloc((size_t)HD * HD * 2);
    short* p_l0w1l = (short*)alloc((size_t)HD * HD * 2);
    short* p_l0w2h = (short*)alloc((size_t)HD * HD * 2);
    short* p_l0w2l = (short*)alloc((size_t)HD * HD * 2);
    short* p_l1w1h = (short*)alloc((size_t)HD * HD * 2);
    short* p_l1w1l = (short*)alloc((size_t)HD * HD * 2);
    short* p_l1w2h = (short*)alloc((size_t)HD * HD * 2);
    short* p_l1w2l = (short*)alloc((size_t)HD * HD * 2);
    short* p_gw1h  = (short*)alloc((size_t)HD * PHD * 2);
    short* p_gw1l  = (short*)alloc((size_t)HD * PHD * 2);

    const int* src = ei;
    const int* dst = ei + N_EDGES;

    hipFuncSetAttribute((const void*)mlp_mfma_kernel,
                        hipFuncAttributeMaxDynamicSharedMemorySize, 131072);

    build_h_kernel<<<N_NODES, 256, 0, stream>>>(x, emb, h);

    hipMemsetAsync(cursor, 0, (size_t)N_NODES * 4, stream);
    count_deg_kernel<<<(N_EDGES + 255) / 256, 256, 0, stream>>>(dst, cursor, N_EDGES);
    scan_kernel<<<1, 1024, 0, stream>>>(cursor, rowptr, N_NODES);
    fill_csr_kernel<<<(N_EDGES + 255) / 256, 256, 0, stream>>>(src, dst, cursor, col, N_EDGES);

    pack_w_kernel<<<32, 256, 0, stream>>>(l0w1, p_l0w1h, p_l0w1l, HD, HD);
    pack_w_kernel<<<32, 256, 0, stream>>>(l0w2, p_l0w2h, p_l0w2l, HD, HD);
    pack_w_kernel<<<32, 256, 0, stream>>>(l1w1, p_l1w1h, p_l1w1l, HD, HD);
    pack_w_kernel<<<32, 256, 0, stream>>>(l1w2, p_l1w2h, p_l1w2l, HD, HD);
    pack_w_kernel<<<16, 256, 0, stream>>>(gw1, p_gw1h, p_gw1l, HD, PHD);

    const int mlp_grid = (N_NODES + 127) / 128;

    // GIN block 0
    aggregate_kernel<<<N_NODES / 4, 256, 0, stream>>>(h, rowptr, col, z, N_NODES);
    mlp_mfma_kernel<<<mlp_grid, 512, 131072, stream>>>(h, z, p_l0w1h, p_l0w1l, l0b1,
                                                       p_l0w2h, p_l0w2l, l0b2, ln0g, ln0b);
    // GIN block 1
    aggregate_kernel<<<N_NODES / 4, 256, 0, stream>>>(h, rowptr, col, z, N_NODES);
    mlp_mfma_kernel<<<mlp_grid, 512, 131072, stream>>>(h, z, p_l1w1h, p_l1w1l, l1b1,
                                                       p_l1w2h, p_l1w2l, l1b2, ln1g, ln1b);

    gate_mfma_kernel<<<(N_NODES + 63) / 64, 256, 0, stream>>>(h, p_gw1h, p_gw1l, gb1, gw2, gb2, gate);
    goff_kernel<<<1, 256, 0, stream>>>(bat, goff, N_NODES);
    pool_kernel<<<NG, 256, 0, stream>>>(h, gate, goff, z, pooled);
    cls_kernel<<<NG, 128, 0, stream>>>(pooled, gf, cw1, cb1, cw2, cb2, (float*)d_out);
}

// Round 7
// 1249.853 us; speedup vs baseline: 1.7638x; 1.3771x over previous
//
// GINCombined r7: mlp 64-row/2-blocks-per-CU, hierarchical CSR scan, 4-way pool, merged pack
#include <hip/hip_runtime.h>
#include <math.h>

#define N_NODES 100000
#define N_EDGES 1600000
#define NG      128
#define HD      256
#define PHD     128
#define GFD     32
#define XW      241
#define LN_EPS  1e-5f
#define SCAN_NB 256
#define CHUNK   ((N_NODES + SCAN_NB - 1) / SCAN_NB)   // 391

typedef __attribute__((ext_vector_type(8))) short bf8_t;  // 8 bf16 (4 VGPR)
typedef __attribute__((ext_vector_type(4))) float f4_t;   // 4 f32 acc

static __device__ __forceinline__ float relu_f(float x){ return fmaxf(x, 0.0f); }

static __device__ __forceinline__ unsigned short f2bf_rn(float v) {
    unsigned int u = __float_as_uint(v);
    unsigned int r = (u + 0x7fffu + ((u >> 16) & 1u)) >> 16;
    return (unsigned short)r;
}
static __device__ __forceinline__ float bf2f(unsigned short h) {
    return __uint_as_float((unsigned int)h << 16);
}

// ---------------- h build ----------------
__global__ void build_h_kernel(const float* __restrict__ x, const float* __restrict__ emb,
                               float* __restrict__ h)
{
    int node = blockIdx.x;
    int tid  = threadIdx.x;
    const float* xr = x + (size_t)node * XW;
    float v;
    if (tid < 240) {
        v = xr[1 + tid];
    } else {
        int t = (int)xr[0];
        v = emb[t * 16 + (tid - 240)];
    }
    h[(size_t)node * HD + tid] = v;
}

// ---------------- CSR build ----------------
__global__ void count_deg_kernel(const int* __restrict__ dst, int* __restrict__ cnt, int e)
{
    int i = blockIdx.x * blockDim.x + threadIdx.x;
    if (i < e) atomicAdd(&cnt[dst[i]], 1);
}

// per-chunk degree sums
__global__ __launch_bounds__(256) void deg_bsum_kernel(const int* __restrict__ deg, int* __restrict__ bsum)
{
    __shared__ int red[256];
    int b = blockIdx.x, t = threadIdx.x;
    int beg = b * CHUNK, end = beg + CHUNK < N_NODES ? beg + CHUNK : N_NODES;
    int s = 0;
    for (int i = beg + t; i < end; i += 256) s += deg[i];
    red[t] = s; __syncthreads();
    for (int off = 128; off > 0; off >>= 1) {
        if (t < off) red[t] += red[t + off];
        __syncthreads();
    }
    if (t == 0) bsum[b] = red[0];
}

// scan 256 chunk sums -> chunk offsets, total -> rowptr[N]
__global__ __launch_bounds__(256) void scan_bsum_kernel(const int* __restrict__ bsum,
                                                        int* __restrict__ boff,
                                                        int* __restrict__ rowptr)
{
    __shared__ int sh[256];
    int t = threadIdx.x;
    sh[t] = bsum[t]; __syncthreads();
    for (int off = 1; off < 256; off <<= 1) {
        int v = sh[t];
        int a = (t >= off) ? sh[t - off] : 0;
        __syncthreads();
        sh[t] = v + a;
        __syncthreads();
    }
    boff[t] = (t > 0) ? sh[t - 1] : 0;
    if (t == 255) rowptr[N_NODES] = sh[255];
}

// per-chunk local prefix + chunk offset -> rowptr & cursor
__global__ __launch_bounds__(256) void fill_rowptr_kernel(const int* __restrict__ deg,
                                                          const int* __restrict__ boff,
                                                          int* __restrict__ rowptr,
                                                          int* __restrict__ cursor)
{
    __shared__ int sh[256];
    int b = blockIdx.x, t = threadIdx.x;
    int beg = b * CHUNK, end = beg + CHUNK < N_NODES ? beg + CHUNK : N_NODES;
    const int per = (CHUNK + 255) / 256;   // 2
    int sbeg = beg + t * per; if (sbeg > end) sbeg = end;
    int send = sbeg + per; if (send > end) send = end;
    int s = 0;
    for (int i = sbeg; i < send; i++) s += deg[i];
    sh[t] = s; __syncthreads();
    for (int off = 1; off < 256; off <<= 1) {
        int v = sh[t];
        int a = (t >= off) ? sh[t - off] : 0;
        __syncthreads();
        sh[t] = v + a;
        __syncthreads();
    }
    int run = boff[b] + ((t > 0) ? sh[t - 1] : 0);
    for (int i = sbeg; i < send; i++) {
        int d = deg[i];
        rowptr[i] = run;
        cursor[i] = run;
        run += d;
    }
}

__global__ void fill_csr_kernel(const int* __restrict__ src, const int* __restrict__ dst,
                                int* __restrict__ cursor, int* __restrict__ col, int e)
{
    int i = blockIdx.x * blockDim.x + threadIdx.x;
    if (i < e) {
        int p = atomicAdd(&cursor[dst[i]], 1);
        col[p] = src[i];
    }
}

// ---------------- aggregate: z = h + sum_neighbors h (4-way unrolled) ----------------
__global__ __launch_bounds__(256) void aggregate_kernel(
    const float* __restrict__ h, const int* __restrict__ rowptr,
    const int* __restrict__ col, float* __restrict__ z, int n)
{
    int node = blockIdx.x * 4 + (threadIdx.x >> 6);
    int lane = threadIdx.x & 63;
    if (node >= n) return;
    size_t base = (size_t)node * HD + lane * 4;
    const int l4 = lane * 4;
    float4 a0 = *(const float4*)&h[base];
    float4 a1 = make_float4(0,0,0,0), a2 = make_float4(0,0,0,0), a3 = make_float4(0,0,0,0);
    int e = rowptr[node], e1 = rowptr[node + 1];
    for (; e + 4 <= e1; e += 4) {
        int s0 = col[e], s1 = col[e+1], s2 = col[e+2], s3 = col[e+3];
        float4 v0 = *(const float4*)&h[(size_t)s0 * HD + l4];
        float4 v1 = *(const float4*)&h[(size_t)s1 * HD + l4];
        float4 v2 = *(const float4*)&h[(size_t)s2 * HD + l4];
        float4 v3 = *(const float4*)&h[(size_t)s3 * HD + l4];
        a0.x += v0.x; a0.y += v0.y; a0.z += v0.z; a0.w += v0.w;
        a1.x += v1.x; a1.y += v1.y; a1.z += v1.z; a1.w += v1.w;
        a2.x += v2.x; a2.y += v2.y; a2.z += v2.z; a2.w += v2.w;
        a3.x += v3.x; a3.y += v3.y; a3.z += v3.z; a3.w += v3.w;
    }
    for (; e < e1; e++) {
        int s = col[e];
        float4 v = *(const float4*)&h[(size_t)s * HD + l4];
        a0.x += v.x; a0.y += v.y; a0.z += v.z; a0.w += v.w;
    }
    a0.x += a1.x + a2.x + a3.x;
    a0.y += a1.y + a2.y + a3.y;
    a0.z += a1.z + a2.z + a3.z;
    a0.w += a1.w + a2.w + a3.w;
    *(float4*)&z[base] = a0;
}

// ---------------- merged weight packing (4 MLP weights + gate) ----------------
static __device__ __forceinline__ void pack_one(const float* __restrict__ w, short* __restrict__ hi,
                                                short* __restrict__ lo, int N, int fbase)
{
    int lane = threadIdx.x & 63;
    int f = fbase * 4 + (threadIdx.x >> 6);
    const int KB = 8;            // K=256 always
    int nb = f / KB, kb = f % KB;
    int n = nb * 16 + (lane & 15);
    int k0 = kb * 32 + (lane >> 4) * 8;
    size_t o = (size_t)f * 512 + lane * 8;
    #pragma unroll
    for (int j = 0; j < 8; j++) {
        float v = w[(size_t)(k0 + j) * N + n];
        unsigned short hb = f2bf_rn(v);
        float hf = bf2f(hb);
        unsigned short lb = f2bf_rn(v - hf);
        hi[o + j] = (short)hb;
        lo[o + j] = (short)lb;
    }
}

__global__ __launch_bounds__(256) void pack_all_kernel(
    const float* __restrict__ w0, const float* __restrict__ w1,
    const float* __restrict__ w2, const float* __restrict__ w3,
    const float* __restrict__ w4,
    short* o0h, short* o0l, short* o1h, short* o1l, short* o2h, short* o2l,
    short* o3h, short* o3l, short* o4h, short* o4l)
{
    int b = blockIdx.x;
    if      (b < 32)  pack_one(w0, o0h, o0l, HD,  b);
    else if (b < 64)  pack_one(w1, o1h, o1l, HD,  b - 32);
    else if (b < 96)  pack_one(w2, o2h, o2l, HD,  b - 64);
    else if (b < 128) pack_one(w3, o3h, o3l, HD,  b - 96);
    else              pack_one(w4, o4h, o4l, PHD, b - 128);
}

// 64-row split-bf16 matmul: acc += (Ahi+Alo)@Bh + Ahi@Bl
// A hi at buf[0:32K), lo at buf[32K:64K), swizzled; B in packed fragment layout.
static __device__ __forceinline__ void mm64(
    f4_t (&acc)[4][4], const char* buf,
    const short* __restrict__ Bh, const short* __restrict__ Bl,
    int wc, int cb, int kg, int lane)
{
    bf8_t bcur[4], bnxt[4];
    // ---- pass A: (Ahi + Alo) * Bh ----
    #pragma unroll
    for (int ni = 0; ni < 4; ni++)
        bcur[ni] = *(const bf8_t*)&Bh[((size_t)((wc*4+ni)*8 + 0))*512 + lane*8];
    for (int kb = 0; kb < 8; kb++) {
        if (kb < 7) {
            #pragma unroll
            for (int ni = 0; ni < 4; ni++)
                bnxt[ni] = *(const bf8_t*)&Bh[((size_t)((wc*4+ni)*8 + kb+1))*512 + lane*8];
        }
        bf8_t ahi[4], alo[4];
        #pragma unroll
        for (int mi = 0; mi < 4; mi++) {
            int row = mi*16 + cb;
            int byte = (row*512 + kb*64 + kg*16) ^ ((row & 7) << 4);
            ahi[mi] = *(const bf8_t*)(buf + byte);
            alo[mi] = *(const bf8_t*)(buf + 32768 + byte);
        }
        #pragma unroll
        for (int mi = 0; mi < 4; mi++)
            #pragma unroll
            for (int ni = 0; ni < 4; ni++)
                acc[mi][ni] = __builtin_amdgcn_mfma_f32_16x16x32_bf16(ahi[mi], bcur[ni], acc[mi][ni], 0, 0, 0);
        #pragma unroll
        for (int mi = 0; mi < 4; mi++)
            #pragma unroll
            for (int ni = 0; ni < 4; ni++)
                acc[mi][ni] = __builtin_amdgcn_mfma_f32_16x16x32_bf16(alo[mi], bcur[ni], acc[mi][ni], 0, 0, 0);
        #pragma unroll
        for (int ni = 0; ni < 4; ni++) bcur[ni] = bnxt[ni];
    }
    // ---- pass B: Ahi * Bl ----
    #pragma unroll
    for (int ni = 0; ni < 4; ni++)
        bcur[ni] = *(const bf8_t*)&Bl[((size_t)((wc*4+ni)*8 + 0))*512 + lane*8];
    for (int kb = 0; kb < 8; kb++) {
        if (kb < 7) {
            #pragma unroll
            for (int ni = 0; ni < 4; ni++)
                bnxt[ni] = *(const bf8_t*)&Bl[((size_t)((wc*4+ni)*8 + kb+1))*512 + lane*8];
        }
        bf8_t ahi[4];
        #pragma unroll
        for (int mi = 0; mi < 4; mi++) {
            int row = mi*16 + cb;
            int byte = (row*512 + kb*64 + kg*16) ^ ((row & 7) << 4);
            ahi[mi] = *(const bf8_t*)(buf + byte);
        }
        #pragma unroll
        for (int mi = 0; mi < 4; mi++)
            #pragma unroll
            for (int ni = 0; ni < 4; ni++)
                acc[mi][ni] = __builtin_amdgcn_mfma_f32_16x16x32_bf16(ahi[mi], bcur[ni], acc[mi][ni], 0, 0, 0);
        #pragma unroll
        for (int ni = 0; ni < 4; ni++) bcur[ni] = bnxt[ni];
    }
}

// ---------------- fused MLP + LN + residual (64 rows/block, 4 waves, 64KB LDS, 2 blocks/CU) ----------------
__global__ __launch_bounds__(256, 4) void mlp_mfma_kernel(
    float* __restrict__ h, const float* __restrict__ z,
    const short* __restrict__ w1h, const short* __restrict__ w1l, const float* __restrict__ b1,
    const short* __restrict__ w2h, const short* __restrict__ w2l, const float* __restrict__ b2,
    const float* __restrict__ lng, const float* __restrict__ lnb)
{
    __shared__ char buf[65536];
    const int tid  = threadIdx.x;
    const int lane = tid & 63;
    const int wv   = tid >> 6;      // 0..3 (also the column group wc)
    const int cb   = lane & 15;
    const int kg   = lane >> 4;
    const long row0 = (long)blockIdx.x * 64;

    // ---- stage z tile [64][256]: split hi/lo, swizzled ----
    for (int rr = 0; rr < 16; rr++) {
        int row = wv * 16 + rr;
        long grow = row0 + row;
        float4 v = make_float4(0.f, 0.f, 0.f, 0.f);
        if (grow < N_NODES) v = *(const float4*)&z[grow * HD + lane * 4];
        ushort4 hi4, lo4;
        unsigned short hb;
        hb = f2bf_rn(v.x); hi4.x = hb; lo4.x = f2bf_rn(v.x - bf2f(hb));
        hb = f2bf_rn(v.y); hi4.y = hb; lo4.y = f2bf_rn(v.y - bf2f(hb));
        hb = f2bf_rn(v.z); hi4.z = hb; lo4.z = f2bf_rn(v.z - bf2f(hb));
        hb = f2bf_rn(v.w); hi4.w = hb; lo4.w = f2bf_rn(v.w - bf2f(hb));
        int byte = (row * 512 + lane * 8) ^ ((row & 7) << 4);
        *(ushort4*)(buf + byte)         = hi4;
        *(ushort4*)(buf + 32768 + byte) = lo4;
    }
    __syncthreads();

    f4_t acc[4][4];
    const f4_t zero4 = {0.f, 0.f, 0.f, 0.f};
    #pragma unroll
    for (int mi = 0; mi < 4; mi++)
        #pragma unroll
        for (int ni = 0; ni < 4; ni++) acc[mi][ni] = zero4;

    mm64(acc, buf, w1h, w1l, wv, cb, kg, lane);
    __syncthreads();

    // ---- t = relu(acc + b1) -> hi/lo swizzled back into buf ----
    {
        float bias1[4];
        #pragma unroll
        for (int ni = 0; ni < 4; ni++) bias1[ni] = b1[wv * 64 + ni * 16 + cb];
        #pragma unroll
        for (int mi = 0; mi < 4; mi++) {
            #pragma unroll
            for (int ni = 0; ni < 4; ni++) {
                int colx2 = (wv * 64 + ni * 16 + cb) * 2;
                #pragma unroll
                for (int j = 0; j < 4; j++) {
                    float t = relu_f(acc[mi][ni][j] + bias1[ni]);
                    int row = mi * 16 + kg * 4 + j;
                    unsigned short hb = f2bf_rn(t);
                    unsigned short lb = f2bf_rn(t - bf2f(hb));
                    int byte = (row * 512 + colx2) ^ ((row & 7) << 4);
                    *(short*)(buf + byte)         = (short)hb;
                    *(short*)(buf + 32768 + byte) = (short)lb;
                }
            }
        }
    }
    __syncthreads();

    #pragma unroll
    for (int mi = 0; mi < 4; mi++)
        #pragma unroll
        for (int ni = 0; ni < 4; ni++) acc[mi][ni] = zero4;

    mm64(acc, buf, w2h, w2l, wv, cb, kg, lane);
    __syncthreads();

    // ---- z2 = acc + b2 -> f32 [64][256] over whole buf (64B-chunk swizzle) ----
    {
        float bias2[4];
        #pragma unroll
        for (int ni = 0; ni < 4; ni++) bias2[ni] = b2[wv * 64 + ni * 16 + cb];
        #pragma unroll
        for (int mi = 0; mi < 4; mi++) {
            #pragma unroll
            for (int ni = 0; ni < 4; ni++) {
                int col = wv * 64 + ni * 16 + cb;
                #pragma unroll
                for (int j = 0; j < 4; j++) {
                    int row = mi * 16 + kg * 4 + j;
                    int byte = (row * 1024 + col * 4) ^ (((row >> 2) & 3) << 6);
                    *(float*)(buf + byte) = acc[mi][ni][j] + bias2[ni];
                }
            }
        }
    }
    __syncthreads();

    // ---- LN + relu + residual ----
    {
        const float4 gv = *(const float4*)&lng[lane * 4];
        const float4 bv = *(const float4*)&lnb[lane * 4];
        for (int rr = 0; rr < 16; rr++) {
            int row = wv * 16 + rr;
            long grow = row0 + row;
            if (grow >= N_NODES) break;
            int byte = (row * 1024 + lane * 16) ^ (((row >> 2) & 3) << 6);
            float4 v = *(const float4*)(buf + byte);
            float s = v.x + v.y + v.z + v.w;
            float q = v.x * v.x + v.y * v.y + v.z * v.z + v.w * v.w;
            #pragma unroll
            for (int off = 32; off > 0; off >>= 1) {
                s += __shfl_xor(s, off, 64);
                q += __shfl_xor(q, off, 64);
            }
            float mu = s * (1.0f / 256.0f);
            float var = q * (1.0f / 256.0f) - mu * mu;
            float rstd = rsqrtf(var + LN_EPS);
            size_t gi = (size_t)grow * HD + lane * 4;
            float4 hv = *(float4*)&h[gi];
            hv.x += relu_f((v.x - mu) * rstd * gv.x + bv.x);
            hv.y += relu_f((v.y - mu) * rstd * gv.y + bv.y);
            hv.z += relu_f((v.z - mu) * rstd * gv.z + bv.z);
            hv.w += relu_f((v.w - mu) * rstd * gv.w + bv.w);
            *(float4*)&h[gi] = hv;
        }
    }
}

// ---------------- gate via split-bf16 MFMA (64 rows/block) ----------------
__global__ __launch_bounds__(256, 2) void gate_mfma_kernel(
    const float* __restrict__ h,
    const short* __restrict__ g1h, const short* __restrict__ g1l, const float* __restrict__ gb1,
    const float* __restrict__ gw2, const float* __restrict__ gb2,
    float* __restrict__ gate)
{
    __shared__ char buf[65536];
    const int tid  = threadIdx.x;
    const int lane = tid & 63;
    const int wv   = tid >> 6;
    const int cb   = lane & 15;
    const int kg   = lane >> 4;
    const long row0 = (long)blockIdx.x * 64;

    for (int rr = 0; rr < 16; rr++) {
        int row = wv * 16 + rr;
        long grow = row0 + row;
        float4 v = make_float4(0.f, 0.f, 0.f, 0.f);
        if (grow < N_NODES) v = *(const float4*)&h[grow * HD + lane * 4];
        ushort4 hi4, lo4;
        unsigned short hb;
        hb = f2bf_rn(v.x); hi4.x = hb; lo4.x = f2bf_rn(v.x - bf2f(hb));
        hb = f2bf_rn(v.y); hi4.y = hb; lo4.y = f2bf_rn(v.y - bf2f(hb));
        hb = f2bf_rn(v.z); hi4.z = hb; lo4.z = f2bf_rn(v.z - bf2f(hb));
        hb = f2bf_rn(v.w); hi4.w = hb; lo4.w = f2bf_rn(v.w - bf2f(hb));
        int byte = (row * 512 + lane * 8) ^ ((row & 7) << 4);
        *(ushort4*)(buf + byte)         = hi4;
        *(ushort4*)(buf + 32768 + byte) = lo4;
    }
    __syncthreads();

    f4_t acc[4][2];
    const f4_t zero4 = {0.f, 0.f, 0.f, 0.f};
    #pragma unroll
    for (int mi = 0; mi < 4; mi++) { acc[mi][0] = zero4; acc[mi][1] = zero4; }

    #pragma unroll
    for (int pass = 0; pass < 3; pass++) {
        const char*  Abase = (pass == 1) ? (buf + 32768) : buf;
        const short* Bsrc  = (pass == 2) ? g1l : g1h;
        for (int kb = 0; kb < 8; kb++) {
            bf8_t a[4], b[2];
            #pragma unroll
            for (int mi = 0; mi < 4; mi++) {
                int row = mi * 16 + cb;
                int byte = (row * 512 + kb * 64 + kg * 16) ^ ((row & 7) << 4);
                a[mi] = *(const bf8_t*)(Abase + byte);
            }
            #pragma unroll
            for (int ni = 0; ni < 2; ni++) {
                int nb = wv * 2 + ni;
                b[ni] = *(const bf8_t*)&Bsrc[(size_t)(nb * 8 + kb) * 512 + lane * 8];
            }
            #pragma unroll
            for (int mi = 0; mi < 4; mi++)
                #pragma unroll
                for (int ni = 0; ni < 2; ni++)
                    acc[mi][ni] = __builtin_amdgcn_mfma_f32_16x16x32_bf16(a[mi], b[ni], acc[mi][ni], 0, 0, 0);
        }
    }
    __syncthreads();

    {
        float* G1 = (float*)buf;
        float bias1[2];
        bias1[0] = gb1[wv * 32 + cb];
        bias1[1] = gb1[wv * 32 + 16 + cb];
        #pragma unroll
        for (int mi = 0; mi < 4; mi++) {
            #pragma unroll
            for (int ni = 0; ni < 2; ni++) {
                int colv = wv * 32 + ni * 16 + cb;
                #pragma unroll
                for (int j = 0; j < 4; j++) {
                    int row = mi * 16 + kg * 4 + j;
                    G1[row * PHD + colv] = relu_f(acc[mi][ni][j] + bias1[ni]);
                }
            }
        }
    }
    __syncthreads();

    {
        const float* G1 = (const float*)buf;
        float2 wv2 = *(const float2*)&gw2[lane * 2];
        float b2v = gb2[0];
        for (int rr = 0; rr < 16; rr++) {
            int row = wv * 16 + rr;
            long grow = row0 + row;
            if (grow >= N_NODES) break;
            float2 t2 = *(const float2*)&G1[row * PHD + lane * 2];
            float p = t2.x * wv2.x + t2.y * wv2.y;
            #pragma unroll
            for (int off = 32; off > 0; off >>= 1) p += __shfl_xor(p, off, 64);
            if (lane == 0) gate[grow] = p + b2v;
        }
    }
}

// ---------------- graph offsets ----------------
__global__ void goff_kernel(const int* __restrict__ batch, int* __restrict__ goff, int n)
{
    int t = threadIdx.x;
    if (t > NG) return;
    int lo = 0, hi = n;
    while (lo < hi) {
        int mid = (lo + hi) >> 1;
        if (batch[mid] < t) lo = mid + 1; else hi = mid;
    }
    goff[t] = lo;
}

// ---------------- softmax-weighted pooling (4 blocks per graph, atomic accumulate) ----------------
__global__ __launch_bounds__(256) void pool_kernel(
    const float* __restrict__ h, const float* __restrict__ gate,
    const int* __restrict__ goff, float* __restrict__ pooled)
{
    __shared__ float red[256];
    __shared__ float m_sh, s_sh;
    int g = blockIdx.x >> 2, q = blockIdx.x & 3;
    int tid = threadIdx.x;
    int beg = goff[g], end = goff[g + 1];
    if (beg >= end) return;   // pooled pre-zeroed

    float lm = -3.4e38f;
    for (int i = beg + tid; i < end; i += 256) lm = fmaxf(lm, gate[i]);
    red[tid] = lm; __syncthreads();
    for (int off = 128; off > 0; off >>= 1) {
        if (tid < off) red[tid] = fmaxf(red[tid], red[tid + off]);
        __syncthreads();
    }
    if (tid == 0) m_sh = red[0];
    __syncthreads();
    float m = m_sh;

    float ls = 0.0f;
    for (int i = beg + tid; i < end; i += 256) ls += expf(gate[i] - m);
    __syncthreads();
    red[tid] = ls; __syncthreads();
    for (int off = 128; off > 0; off >>= 1) {
        if (tid < off) red[tid] += red[tid + off];
        __syncthreads();
    }
    if (tid == 0) s_sh = red[0];
    __syncthreads();
    float inv_s = 1.0f / s_sh;

    float acc = 0.0f;
    for (int i = beg + q; i < end; i += 4) {
        float a = expf(gate[i] - m);
        acc += a * h[(size_t)i * HD + tid];
    }
    atomicAdd(&pooled[(size_t)g * HD + tid], acc * inv_s);
}

// ---------------- classifier ----------------
__global__ __launch_bounds__(128) void cls_kernel(
    const float* __restrict__ pooled, const float* __restrict__ gf,
    const float* __restrict__ w1, const float* __restrict__ b1,
    const float* __restrict__ w2, const float* __restrict__ b2,
    float* __restrict__ out)
{
    __shared__ float r0[128], r1[128];
    int g = blockIdx.x, c = threadIdx.x;
    float acc = b1[c];
    const float* pr = pooled + (size_t)g * HD;
    for (int k = 0; k < HD; k++) acc += pr[k] * w1[k * PHD + c];
    const float* gr = gf + g * GFD;
    for (int k = 0; k < GFD; k++) acc += gr[k] * w1[(HD + k) * PHD + c];
    float t = relu_f(acc);
    r0[c] = t * w2[c * 2 + 0];
    r1[c] = t * w2[c * 2 + 1];
    __syncthreads();
    for (int off = 64; off > 0; off >>= 1) {
        if (c < off) { r0[c] += r0[c + off]; r1[c] += r1[c + off]; }
        __syncthreads();
    }
    if (c == 0) {
        out[g * 2 + 0] = r0[0] + b2[0];
        out[g * 2 + 1] = r1[0] + b2[1];
    }
}

extern "C" void kernel_launch(void* const* d_in, const int* in_sizes, int n_in,
                              void* d_out, int out_size, void* d_ws, size_t ws_size,
                              hipStream_t stream)
{
    const float* x    = (const float*)d_in[0];
    const int*   ei   = (const int*)d_in[1];
    const int*   bat  = (const int*)d_in[2];
    const float* gf   = (const float*)d_in[3];
    const float* emb  = (const float*)d_in[4];
    const float* l0w1 = (const float*)d_in[5];
    const float* l0b1 = (const float*)d_in[6];
    const float* l0w2 = (const float*)d_in[7];
    const float* l0b2 = (const float*)d_in[8];
    const float* ln0g = (const float*)d_in[9];
    const float* ln0b = (const float*)d_in[10];
    const float* l1w1 = (const float*)d_in[11];
    const float* l1b1 = (const float*)d_in[12];
    const float* l1w2 = (const float*)d_in[13];
    const float* l1b2 = (const float*)d_in[14];
    const float* ln1g = (const float*)d_in[15];
    const float* ln1b = (const float*)d_in[16];
    const float* gw1  = (const float*)d_in[17];
    const float* gb1  = (const float*)d_in[18];
    const float* gw2  = (const float*)d_in[19];
    const float* gb2  = (const float*)d_in[20];
    const float* cw1  = (const float*)d_in[21];
    const float* cb1  = (const float*)d_in[22];
    const float* cw2  = (const float*)d_in[23];
    const float* cb2  = (const float*)d_in[24];

    char* ws = (char*)d_ws;
    size_t off = 0;
    auto alloc = [&](size_t bytes) {
        void* p = ws + off;
        off += (bytes + 255) & ~(size_t)255;
        return p;
    };
    float* h      = (float*)alloc((size_t)N_NODES * HD * 4);
    float* z      = (float*)alloc((size_t)N_NODES * HD * 4);
    float* gate   = (float*)alloc((size_t)N_NODES * 4);
    int*   rowptr = (int*)alloc((size_t)(N_NODES + 1) * 4);
    int*   cursor = (int*)alloc((size_t)N_NODES * 4);
    int*   deg    = (int*)alloc((size_t)N_NODES * 4);
    int*   col    = (int*)alloc((size_t)N_EDGES * 4);
    int*   goff   = (int*)alloc((NG + 1) * 4);
    float* pooled = (float*)alloc((size_t)NG * HD * 4);
    int*   bsum   = (int*)alloc(SCAN_NB * 4);
    int*   boff   = (int*)alloc(SCAN_NB * 4);
    short* p_l0w1h = (short*)alloc((size_t)HD * HD * 2);
    short* p_l0w1l = (short*)alloc((size_t)HD * HD * 2);
    short* p_l0w2h = (short*)alloc((size_t)HD * HD * 2);
    short* p_l0w2l = (short*)alloc((size_t)HD * HD * 2);
    short* p_l1w1h = (short*)alloc((size_t)HD * HD * 2);
    short* p_l1w1l = (short*)alloc((size_t)HD * HD * 2);
    short* p_l1w2h = (short*)alloc((size_t)HD * HD * 2);
    short* p_l1w2l = (short*)alloc((size_t)HD * HD * 2);
    short* p_gw1h  = (short*)alloc((size_t)HD * PHD * 2);
    short* p_gw1l  = (short*)alloc((size_t)HD * PHD * 2);

    const int* src = ei;
    const int* dst = ei + N_EDGES;

    build_h_kernel<<<N_NODES, 256, 0, stream>>>(x, emb, h);

    // CSR build (hierarchical scan)
    hipMemsetAsync(deg, 0, (size_t)N_NODES * 4, stream);
    count_deg_kernel<<<(N_EDGES + 255) / 256, 256, 0, stream>>>(dst, deg, N_EDGES);
    deg_bsum_kernel<<<SCAN_NB, 256, 0, stream>>>(deg, bsum);
    scan_bsum_kernel<<<1, 256, 0, stream>>>(bsum, boff, rowptr);
    fill_rowptr_kernel<<<SCAN_NB, 256, 0, stream>>>(deg, boff, rowptr, cursor);
    fill_csr_kernel<<<(N_EDGES + 255) / 256, 256, 0, stream>>>(src, dst, cursor, col, N_EDGES);

    pack_all_kernel<<<144, 256, 0, stream>>>(l0w1, l0w2, l1w1, l1w2, gw1,
                                             p_l0w1h, p_l0w1l, p_l0w2h, p_l0w2l,
                                             p_l1w1h, p_l1w1l, p_l1w2h, p_l1w2l,
                                             p_gw1h, p_gw1l);

    const int mlp_grid = (N_NODES + 63) / 64;

    // GIN block 0
    aggregate_kernel<<<N_NODES / 4, 256, 0, stream>>>(h, rowptr, col, z, N_NODES);
    mlp_mfma_kernel<<<mlp_grid, 256, 0, stream>>>(h, z, p_l0w1h, p_l0w1l, l0b1,
                                                  p_l0w2h, p_l0w2l, l0b2, ln0g, ln0b);
    // GIN block 1
    aggregate_kernel<<<N_NODES / 4, 256, 0, stream>>>(h, rowptr, col, z, N_NODES);
    mlp_mfma_kernel<<<mlp_grid, 256, 0, stream>>>(h, z, p_l1w1h, p_l1w1l, l1b1,
                                                  p_l1w2h, p_l1w2l, l1b2, ln1g, ln1b);

    gate_mfma_kernel<<<mlp_grid, 256, 0, stream>>>(h, p_gw1h, p_gw1l, gb1, gw2, gb2, gate);
    goff_kernel<<<1, 256, 0, stream>>>(bat, goff, N_NODES);
    hipMemsetAsync(pooled, 0, (size_t)NG * HD * 4, stream);
    pool_kernel<<<NG * 4, 256, 0, stream>>>(h, gate, goff, pooled);
    cls_kernel<<<NG, 128, 0, stream>>>(pooled, gf, cw1, cb1, cw2, cb2, (float*)d_out);
}

// Round 8
// 1026.136 us; speedup vs baseline: 2.1484x; 1.2180x over previous
//
// GINCombined r8: bf16 h-mirror for the edge gather (halves aggregate traffic)
#include <hip/hip_runtime.h>
#include <math.h>

#define N_NODES 100000
#define N_EDGES 1600000
#define NG      128
#define HD      256
#define PHD     128
#define GFD     32
#define XW      241
#define LN_EPS  1e-5f
#define SCAN_NB 256
#define CHUNK   ((N_NODES + SCAN_NB - 1) / SCAN_NB)   // 391

typedef __attribute__((ext_vector_type(8))) short bf8_t;  // 8 bf16 (4 VGPR)
typedef __attribute__((ext_vector_type(4))) float f4_t;   // 4 f32 acc

static __device__ __forceinline__ float relu_f(float x){ return fmaxf(x, 0.0f); }

static __device__ __forceinline__ unsigned short f2bf_rn(float v) {
    unsigned int u = __float_as_uint(v);
    unsigned int r = (u + 0x7fffu + ((u >> 16) & 1u)) >> 16;
    return (unsigned short)r;
}
static __device__ __forceinline__ float bf2f(unsigned short h) {
    return __uint_as_float((unsigned int)h << 16);
}

// ---------------- h build (fp32 + bf16 mirror) ----------------
__global__ void build_h_kernel(const float* __restrict__ x, const float* __restrict__ emb,
                               float* __restrict__ h, unsigned short* __restrict__ h16)
{
    int node = blockIdx.x;
    int tid  = threadIdx.x;
    const float* xr = x + (size_t)node * XW;
    float v;
    if (tid < 240) {
        v = xr[1 + tid];
    } else {
        int t = (int)xr[0];
        v = emb[t * 16 + (tid - 240)];
    }
    h[(size_t)node * HD + tid] = v;
    h16[(size_t)node * HD + tid] = f2bf_rn(v);
}

// ---------------- CSR build ----------------
__global__ void count_deg_kernel(const int* __restrict__ dst, int* __restrict__ cnt, int e)
{
    int i = blockIdx.x * blockDim.x + threadIdx.x;
    if (i < e) atomicAdd(&cnt[dst[i]], 1);
}

__global__ __launch_bounds__(256) void deg_bsum_kernel(const int* __restrict__ deg, int* __restrict__ bsum)
{
    __shared__ int red[256];
    int b = blockIdx.x, t = threadIdx.x;
    int beg = b * CHUNK, end = beg + CHUNK < N_NODES ? beg + CHUNK : N_NODES;
    int s = 0;
    for (int i = beg + t; i < end; i += 256) s += deg[i];
    red[t] = s; __syncthreads();
    for (int off = 128; off > 0; off >>= 1) {
        if (t < off) red[t] += red[t + off];
        __syncthreads();
    }
    if (t == 0) bsum[b] = red[0];
}

__global__ __launch_bounds__(256) void scan_bsum_kernel(const int* __restrict__ bsum,
                                                        int* __restrict__ boff,
                                                        int* __restrict__ rowptr)
{
    __shared__ int sh[256];
    int t = threadIdx.x;
    sh[t] = bsum[t]; __syncthreads();
    for (int off = 1; off < 256; off <<= 1) {
        int v = sh[t];
        int a = (t >= off) ? sh[t - off] : 0;
        __syncthreads();
        sh[t] = v + a;
        __syncthreads();
    }
    boff[t] = (t > 0) ? sh[t - 1] : 0;
    if (t == 255) rowptr[N_NODES] = sh[255];
}

__global__ __launch_bounds__(256) void fill_rowptr_kernel(const int* __restrict__ deg,
                                                          const int* __restrict__ boff,
                                                          int* __restrict__ rowptr,
                                                          int* __restrict__ cursor)
{
    __shared__ int sh[256];
    int b = blockIdx.x, t = threadIdx.x;
    int beg = b * CHUNK, end = beg + CHUNK < N_NODES ? beg + CHUNK : N_NODES;
    const int per = (CHUNK + 255) / 256;   // 2
    int sbeg = beg + t * per; if (sbeg > end) sbeg = end;
    int send = sbeg + per; if (send > end) send = end;
    int s = 0;
    for (int i = sbeg; i < send; i++) s += deg[i];
    sh[t] = s; __syncthreads();
    for (int off = 1; off < 256; off <<= 1) {
        int v = sh[t];
        int a = (t >= off) ? sh[t - off] : 0;
        __syncthreads();
        sh[t] = v + a;
        __syncthreads();
    }
    int run = boff[b] + ((t > 0) ? sh[t - 1] : 0);
    for (int i = sbeg; i < send; i++) {
        int d = deg[i];
        rowptr[i] = run;
        cursor[i] = run;
        run += d;
    }
}

__global__ void fill_csr_kernel(const int* __restrict__ src, const int* __restrict__ dst,
                                int* __restrict__ cursor, int* __restrict__ col, int e)
{
    int i = blockIdx.x * blockDim.x + threadIdx.x;
    if (i < e) {
        int p = atomicAdd(&cursor[dst[i]], 1);
        col[p] = src[i];
    }
}

// ---------------- aggregate: z = h + sum_neighbors h16 (bf16 gather, 4-way unrolled) ----------------
__global__ __launch_bounds__(256) void aggregate_kernel(
    const float* __restrict__ h, const unsigned short* __restrict__ h16,
    const int* __restrict__ rowptr, const int* __restrict__ col,
    float* __restrict__ z, int n)
{
    int node = blockIdx.x * 4 + (threadIdx.x >> 6);
    int lane = threadIdx.x & 63;
    if (node >= n) return;
    const int l4 = lane * 4;
    size_t base = (size_t)node * HD + l4;
    float4 a0 = *(const float4*)&h[base];   // self term exact (fp32)
    float4 a1 = make_float4(0,0,0,0), a2 = make_float4(0,0,0,0), a3 = make_float4(0,0,0,0);
    int e = rowptr[node], e1 = rowptr[node + 1];
    for (; e + 4 <= e1; e += 4) {
        int s0 = col[e], s1 = col[e+1], s2 = col[e+2], s3 = col[e+3];
        ushort4 u0 = *(const ushort4*)&h16[(size_t)s0 * HD + l4];
        ushort4 u1 = *(const ushort4*)&h16[(size_t)s1 * HD + l4];
        ushort4 u2 = *(const ushort4*)&h16[(size_t)s2 * HD + l4];
        ushort4 u3 = *(const ushort4*)&h16[(size_t)s3 * HD + l4];
        a0.x += bf2f(u0.x); a0.y += bf2f(u0.y); a0.z += bf2f(u0.z); a0.w += bf2f(u0.w);
        a1.x += bf2f(u1.x); a1.y += bf2f(u1.y); a1.z += bf2f(u1.z); a1.w += bf2f(u1.w);
        a2.x += bf2f(u2.x); a2.y += bf2f(u2.y); a2.z += bf2f(u2.z); a2.w += bf2f(u2.w);
        a3.x += bf2f(u3.x); a3.y += bf2f(u3.y); a3.z += bf2f(u3.z); a3.w += bf2f(u3.w);
    }
    for (; e < e1; e++) {
        int s = col[e];
        ushort4 u = *(const ushort4*)&h16[(size_t)s * HD + l4];
        a0.x += bf2f(u.x); a0.y += bf2f(u.y); a0.z += bf2f(u.z); a0.w += bf2f(u.w);
    }
    a0.x += a1.x + a2.x + a3.x;
    a0.y += a1.y + a2.y + a3.y;
    a0.z += a1.z + a2.z + a3.z;
    a0.w += a1.w + a2.w + a3.w;
    *(float4*)&z[base] = a0;
}

// ---------------- merged weight packing (4 MLP weights + gate) ----------------
static __device__ __forceinline__ void pack_one(const float* __restrict__ w, short* __restrict__ hi,
                                                short* __restrict__ lo, int N, int fbase)
{
    int lane = threadIdx.x & 63;
    int f = fbase * 4 + (threadIdx.x >> 6);
    const int KB = 8;            // K=256 always
    int nb = f / KB, kb = f % KB;
    int n = nb * 16 + (lane & 15);
    int k0 = kb * 32 + (lane >> 4) * 8;
    size_t o = (size_t)f * 512 + lane * 8;
    #pragma unroll
    for (int j = 0; j < 8; j++) {
        float v = w[(size_t)(k0 + j) * N + n];
        unsigned short hb = f2bf_rn(v);
        float hf = bf2f(hb);
        unsigned short lb = f2bf_rn(v - hf);
        hi[o + j] = (short)hb;
        lo[o + j] = (short)lb;
    }
}

__global__ __launch_bounds__(256) void pack_all_kernel(
    const float* __restrict__ w0, const float* __restrict__ w1,
    const float* __restrict__ w2, const float* __restrict__ w3,
    const float* __restrict__ w4,
    short* o0h, short* o0l, short* o1h, short* o1l, short* o2h, short* o2l,
    short* o3h, short* o3l, short* o4h, short* o4l)
{
    int b = blockIdx.x;
    if      (b < 32)  pack_one(w0, o0h, o0l, HD,  b);
    else if (b < 64)  pack_one(w1, o1h, o1l, HD,  b - 32);
    else if (b < 96)  pack_one(w2, o2h, o2l, HD,  b - 64);
    else if (b < 128) pack_one(w3, o3h, o3l, HD,  b - 96);
    else              pack_one(w4, o4h, o4l, PHD, b - 128);
}

// 64-row split-bf16 matmul: acc += (Ahi+Alo)@Bh + Ahi@Bl
static __device__ __forceinline__ void mm64(
    f4_t (&acc)[4][4], const char* buf,
    const short* __restrict__ Bh, const short* __restrict__ Bl,
    int wc, int cb, int kg, int lane)
{
    bf8_t bcur[4], bnxt[4];
    #pragma unroll
    for (int ni = 0; ni < 4; ni++)
        bcur[ni] = *(const bf8_t*)&Bh[((size_t)((wc*4+ni)*8 + 0))*512 + lane*8];
    for (int kb = 0; kb < 8; kb++) {
        if (kb < 7) {
            #pragma unroll
            for (int ni = 0; ni < 4; ni++)
                bnxt[ni] = *(const bf8_t*)&Bh[((size_t)((wc*4+ni)*8 + kb+1))*512 + lane*8];
        }
        bf8_t ahi[4], alo[4];
        #pragma unroll
        for (int mi = 0; mi < 4; mi++) {
            int row = mi*16 + cb;
            int byte = (row*512 + kb*64 + kg*16) ^ ((row & 7) << 4);
            ahi[mi] = *(const bf8_t*)(buf + byte);
            alo[mi] = *(const bf8_t*)(buf + 32768 + byte);
        }
        #pragma unroll
        for (int mi = 0; mi < 4; mi++)
            #pragma unroll
            for (int ni = 0; ni < 4; ni++)
                acc[mi][ni] = __builtin_amdgcn_mfma_f32_16x16x32_bf16(ahi[mi], bcur[ni], acc[mi][ni], 0, 0, 0);
        #pragma unroll
        for (int mi = 0; mi < 4; mi++)
            #pragma unroll
            for (int ni = 0; ni < 4; ni++)
                acc[mi][ni] = __builtin_amdgcn_mfma_f32_16x16x32_bf16(alo[mi], bcur[ni], acc[mi][ni], 0, 0, 0);
        #pragma unroll
        for (int ni = 0; ni < 4; ni++) bcur[ni] = bnxt[ni];
    }
    #pragma unroll
    for (int ni = 0; ni < 4; ni++)
        bcur[ni] = *(const bf8_t*)&Bl[((size_t)((wc*4+ni)*8 + 0))*512 + lane*8];
    for (int kb = 0; kb < 8; kb++) {
        if (kb < 7) {
            #pragma unroll
            for (int ni = 0; ni < 4; ni++)
                bnxt[ni] = *(const bf8_t*)&Bl[((size_t)((wc*4+ni)*8 + kb+1))*512 + lane*8];
        }
        bf8_t ahi[4];
        #pragma unroll
        for (int mi = 0; mi < 4; mi++) {
            int row = mi*16 + cb;
            int byte = (row*512 + kb*64 + kg*16) ^ ((row & 7) << 4);
            ahi[mi] = *(const bf8_t*)(buf + byte);
        }
        #pragma unroll
        for (int mi = 0; mi < 4; mi++)
            #pragma unroll
            for (int ni = 0; ni < 4; ni++)
                acc[mi][ni] = __builtin_amdgcn_mfma_f32_16x16x32_bf16(ahi[mi], bcur[ni], acc[mi][ni], 0, 0, 0);
        #pragma unroll
        for (int ni = 0; ni < 4; ni++) bcur[ni] = bnxt[ni];
    }
}

// ---------------- fused MLP + LN + residual (64 rows/block, 2 blocks/CU); also refresh h16 ----------------
__global__ __launch_bounds__(256, 4) void mlp_mfma_kernel(
    float* __restrict__ h, unsigned short* __restrict__ h16, const float* __restrict__ z,
    const short* __restrict__ w1h, const short* __restrict__ w1l, const float* __restrict__ b1,
    const short* __restrict__ w2h, const short* __restrict__ w2l, const float* __restrict__ b2,
    const float* __restrict__ lng, const float* __restrict__ lnb)
{
    __shared__ char buf[65536];
    const int tid  = threadIdx.x;
    const int lane = tid & 63;
    const int wv   = tid >> 6;      // 0..3 (also the column group wc)
    const int cb   = lane & 15;
    const int kg   = lane >> 4;
    const long row0 = (long)blockIdx.x * 64;

    // ---- stage z tile [64][256]: split hi/lo, swizzled ----
    for (int rr = 0; rr < 16; rr++) {
        int row = wv * 16 + rr;
        long grow = row0 + row;
        float4 v = make_float4(0.f, 0.f, 0.f, 0.f);
        if (grow < N_NODES) v = *(const float4*)&z[grow * HD + lane * 4];
        ushort4 hi4, lo4;
        unsigned short hb;
        hb = f2bf_rn(v.x); hi4.x = hb; lo4.x = f2bf_rn(v.x - bf2f(hb));
        hb = f2bf_rn(v.y); hi4.y = hb; lo4.y = f2bf_rn(v.y - bf2f(hb));
        hb = f2bf_rn(v.z); hi4.z = hb; lo4.z = f2bf_rn(v.z - bf2f(hb));
        hb = f2bf_rn(v.w); hi4.w = hb; lo4.w = f2bf_rn(v.w - bf2f(hb));
        int byte = (row * 512 + lane * 8) ^ ((row & 7) << 4);
        *(ushort4*)(buf + byte)         = hi4;
        *(ushort4*)(buf + 32768 + byte) = lo4;
    }
    __syncthreads();

    f4_t acc[4][4];
    const f4_t zero4 = {0.f, 0.f, 0.f, 0.f};
    #pragma unroll
    for (int mi = 0; mi < 4; mi++)
        #pragma unroll
        for (int ni = 0; ni < 4; ni++) acc[mi][ni] = zero4;

    mm64(acc, buf, w1h, w1l, wv, cb, kg, lane);
    __syncthreads();

    {
        float bias1[4];
        #pragma unroll
        for (int ni = 0; ni < 4; ni++) bias1[ni] = b1[wv * 64 + ni * 16 + cb];
        #pragma unroll
        for (int mi = 0; mi < 4; mi++) {
            #pragma unroll
            for (int ni = 0; ni < 4; ni++) {
                int colx2 = (wv * 64 + ni * 16 + cb) * 2;
                #pragma unroll
                for (int j = 0; j < 4; j++) {
                    float t = relu_f(acc[mi][ni][j] + bias1[ni]);
                    int row = mi * 16 + kg * 4 + j;
                    unsigned short hb = f2bf_rn(t);
                    unsigned short lb = f2bf_rn(t - bf2f(hb));
                    int byte = (row * 512 + colx2) ^ ((row & 7) << 4);
                    *(short*)(buf + byte)         = (short)hb;
                    *(short*)(buf + 32768 + byte) = (short)lb;
                }
            }
        }
    }
    __syncthreads();

    #pragma unroll
    for (int mi = 0; mi < 4; mi++)
        #pragma unroll
        for (int ni = 0; ni < 4; ni++) acc[mi][ni] = zero4;

    mm64(acc, buf, w2h, w2l, wv, cb, kg, lane);
    __syncthreads();

    {
        float bias2[4];
        #pragma unroll
        for (int ni = 0; ni < 4; ni++) bias2[ni] = b2[wv * 64 + ni * 16 + cb];
        #pragma unroll
        for (int mi = 0; mi < 4; mi++) {
            #pragma unroll
            for (int ni = 0; ni < 4; ni++) {
                int col = wv * 64 + ni * 16 + cb;
                #pragma unroll
                for (int j = 0; j < 4; j++) {
                    int row = mi * 16 + kg * 4 + j;
                    int byte = (row * 1024 + col * 4) ^ (((row >> 2) & 3) << 6);
                    *(float*)(buf + byte) = acc[mi][ni][j] + bias2[ni];
                }
            }
        }
    }
    __syncthreads();

    // ---- LN + relu + residual; write h fp32 + h16 mirror ----
    {
        const float4 gv = *(const float4*)&lng[lane * 4];
        const float4 bv = *(const float4*)&lnb[lane * 4];
        for (int rr = 0; rr < 16; rr++) {
            int row = wv * 16 + rr;
            long grow = row0 + row;
            if (grow >= N_NODES) break;
            int byte = (row * 1024 + lane * 16) ^ (((row >> 2) & 3) << 6);
            float4 v = *(const float4*)(buf + byte);
            float s = v.x + v.y + v.z + v.w;
            float q = v.x * v.x + v.y * v.y + v.z * v.z + v.w * v.w;
            #pragma unroll
            for (int off = 32; off > 0; off >>= 1) {
                s += __shfl_xor(s, off, 64);
                q += __shfl_xor(q, off, 64);
            }
            float mu = s * (1.0f / 256.0f);
            float var = q * (1.0f / 256.0f) - mu * mu;
            float rstd = rsqrtf(var + LN_EPS);
            size_t gi = (size_t)grow * HD + lane * 4;
            float4 hv = *(float4*)&h[gi];
            hv.x += relu_f((v.x - mu) * rstd * gv.x + bv.x);
            hv.y += relu_f((v.y - mu) * rstd * gv.y + bv.y);
            hv.z += relu_f((v.z - mu) * rstd * gv.z + bv.z);
            hv.w += relu_f((v.w - mu) * rstd * gv.w + bv.w);
            *(float4*)&h[gi] = hv;
            ushort4 m16;
            m16.x = f2bf_rn(hv.x); m16.y = f2bf_rn(hv.y);
            m16.z = f2bf_rn(hv.z); m16.w = f2bf_rn(hv.w);
            *(ushort4*)&h16[gi] = m16;
        }
    }
}

// ---------------- gate via split-bf16 MFMA (64 rows/block) ----------------
__global__ __launch_bounds__(256, 2) void gate_mfma_kernel(
    const float* __restrict__ h,
    const short* __restrict__ g1h, const short* __restrict__ g1l, const float* __restrict__ gb1,
    const float* __restrict__ gw2, const float* __restrict__ gb2,
    float* __restrict__ gate)
{
    __shared__ char buf[65536];
    const int tid  = threadIdx.x;
    const int lane = tid & 63;
    const int wv   = tid >> 6;
    const int cb   = lane & 15;
    const int kg   = lane >> 4;
    const long row0 = (long)blockIdx.x * 64;

    for (int rr = 0; rr < 16; rr++) {
        int row = wv * 16 + rr;
        long grow = row0 + row;
        float4 v = make_float4(0.f, 0.f, 0.f, 0.f);
        if (grow < N_NODES) v = *(const float4*)&h[grow * HD + lane * 4];
        ushort4 hi4, lo4;
        unsigned short hb;
        hb = f2bf_rn(v.x); hi4.x = hb; lo4.x = f2bf_rn(v.x - bf2f(hb));
        hb = f2bf_rn(v.y); hi4.y = hb; lo4.y = f2bf_rn(v.y - bf2f(hb));
        hb = f2bf_rn(v.z); hi4.z = hb; lo4.z = f2bf_rn(v.z - bf2f(hb));
        hb = f2bf_rn(v.w); hi4.w = hb; lo4.w = f2bf_rn(v.w - bf2f(hb));
        int byte = (row * 512 + lane * 8) ^ ((row & 7) << 4);
        *(ushort4*)(buf + byte)         = hi4;
        *(ushort4*)(buf + 32768 + byte) = lo4;
    }
    __syncthreads();

    f4_t acc[4][2];
    const f4_t zero4 = {0.f, 0.f, 0.f, 0.f};
    #pragma unroll
    for (int mi = 0; mi < 4; mi++) { acc[mi][0] = zero4; acc[mi][1] = zero4; }

    #pragma unroll
    for (int pass = 0; pass < 3; pass++) {
        const char*  Abase = (pass == 1) ? (buf + 32768) : buf;
        const short* Bsrc  = (pass == 2) ? g1l : g1h;
        for (int kb = 0; kb < 8; kb++) {
            bf8_t a[4], b[2];
            #pragma unroll
            for (int mi = 0; mi < 4; mi++) {
                int row = mi * 16 + cb;
                int byte = (row * 512 + kb * 64 + kg * 16) ^ ((row & 7) << 4);
                a[mi] = *(const bf8_t*)(Abase + byte);
            }
            #pragma unroll
            for (int ni = 0; ni < 2; ni++) {
                int nb = wv * 2 + ni;
                b[ni] = *(const bf8_t*)&Bsrc[(size_t)(nb * 8 + kb) * 512 + lane * 8];
            }
            #pragma unroll
            for (int mi = 0; mi < 4; mi++)
                #pragma unroll
                for (int ni = 0; ni < 2; ni++)
                    acc[mi][ni] = __builtin_amdgcn_mfma_f32_16x16x32_bf16(a[mi], b[ni], acc[mi][ni], 0, 0, 0);
        }
    }
    __syncthreads();

    {
        float* G1 = (float*)buf;
        float bias1[2];
        bias1[0] = gb1[wv * 32 + cb];
        bias1[1] = gb1[wv * 32 + 16 + cb];
        #pragma unroll
        for (int mi = 0; mi < 4; mi++) {
            #pragma unroll
            for (int ni = 0; ni < 2; ni++) {
                int colv = wv * 32 + ni * 16 + cb;
                #pragma unroll
                for (int j = 0; j < 4; j++) {
                    int row = mi * 16 + kg * 4 + j;
                    G1[row * PHD + colv] = relu_f(acc[mi][ni][j] + bias1[ni]);
                }
            }
        }
    }
    __syncthreads();

    {
        const float* G1 = (const float*)buf;
        float2 wv2 = *(const float2*)&gw2[lane * 2];
        float b2v = gb2[0];
        for (int rr = 0; rr < 16; rr++) {
            int row = wv * 16 + rr;
            long grow = row0 + row;
            if (grow >= N_NODES) break;
            float2 t2 = *(const float2*)&G1[row * PHD + lane * 2];
            float p = t2.x * wv2.x + t2.y * wv2.y;
            #pragma unroll
            for (int off = 32; off > 0; off >>= 1) p += __shfl_xor(p, off, 64);
            if (lane == 0) gate[grow] = p + b2v;
        }
    }
}

// ---------------- graph offsets ----------------
__global__ void goff_kernel(const int* __restrict__ batch, int* __restrict__ goff, int n)
{
    int t = threadIdx.x;
    if (t > NG) return;
    int lo = 0, hi = n;
    while (lo < hi) {
        int mid = (lo + hi) >> 1;
        if (batch[mid] < t) lo = mid + 1; else hi = mid;
    }
    goff[t] = lo;
}

// ---------------- softmax-weighted pooling (4 blocks per graph, atomic accumulate) ----------------
__global__ __launch_bounds__(256) void pool_kernel(
    const float* __restrict__ h, const float* __restrict__ gate,
    const int* __restrict__ goff, float* __restrict__ pooled)
{
    __shared__ float red[256];
    __shared__ float m_sh, s_sh;
    int g = blockIdx.x >> 2, q = blockIdx.x & 3;
    int tid = threadIdx.x;
    int beg = goff[g], end = goff[g + 1];
    if (beg >= end) return;   // pooled pre-zeroed

    float lm = -3.4e38f;
    for (int i = beg + tid; i < end; i += 256) lm = fmaxf(lm, gate[i]);
    red[tid] = lm; __syncthreads();
    for (int off = 128; off > 0; off >>= 1) {
        if (tid < off) red[tid] = fmaxf(red[tid], red[tid + off]);
        __syncthreads();
    }
    if (tid == 0) m_sh = red[0];
    __syncthreads();
    float m = m_sh;

    float ls = 0.0f;
    for (int i = beg + tid; i < end; i += 256) ls += expf(gate[i] - m);
    __syncthreads();
    red[tid] = ls; __syncthreads();
    for (int off = 128; off > 0; off >>= 1) {
        if (tid < off) red[tid] += red[tid + off];
        __syncthreads();
    }
    if (tid == 0) s_sh = red[0];
    __syncthreads();
    float inv_s = 1.0f / s_sh;

    float acc = 0.0f;
    for (int i = beg + q; i < end; i += 4) {
        float a = expf(gate[i] - m);
        acc += a * h[(size_t)i * HD + tid];
    }
    atomicAdd(&pooled[(size_t)g * HD + tid], acc * inv_s);
}

// ---------------- classifier ----------------
__global__ __launch_bounds__(128) void cls_kernel(
    const float* __restrict__ pooled, const float* __restrict__ gf,
    const float* __restrict__ w1, const float* __restrict__ b1,
    const float* __restrict__ w2, const float* __restrict__ b2,
    float* __restrict__ out)
{
    __shared__ float r0[128], r1[128];
    int g = blockIdx.x, c = threadIdx.x;
    float acc = b1[c];
    const float* pr = pooled + (size_t)g * HD;
    for (int k = 0; k < HD; k++) acc += pr[k] * w1[k * PHD + c];
    const float* gr = gf + g * GFD;
    for (int k = 0; k < GFD; k++) acc += gr[k] * w1[(HD + k) * PHD + c];
    float t = relu_f(acc);
    r0[c] = t * w2[c * 2 + 0];
    r1[c] = t * w2[c * 2 + 1];
    __syncthreads();
    for (int off = 64; off > 0; off >>= 1) {
        if (c < off) { r0[c] += r0[c + off]; r1[c] += r1[c + off]; }
        __syncthreads();
    }
    if (c == 0) {
        out[g * 2 + 0] = r0[0] + b2[0];
        out[g * 2 + 1] = r1[0] + b2[1];
    }
}

extern "C" void kernel_launch(void* const* d_in, const int* in_sizes, int n_in,
                              void* d_out, int out_size, void* d_ws, size_t ws_size,
                              hipStream_t stream)
{
    const float* x    = (const float*)d_in[0];
    const int*   ei   = (const int*)d_in[1];
    const int*   bat  = (const int*)d_in[2];
    const float* gf   = (const float*)d_in[3];
    const float* emb  = (const float*)d_in[4];
    const float* l0w1 = (const float*)d_in[5];
    const float* l0b1 = (const float*)d_in[6];
    const float* l0w2 = (const float*)d_in[7];
    const float* l0b2 = (const float*)d_in[8];
    const float* ln0g = (const float*)d_in[9];
    const float* ln0b = (const float*)d_in[10];
    const float* l1w1 = (const float*)d_in[11];
    const float* l1b1 = (const float*)d_in[12];
    const float* l1w2 = (const float*)d_in[13];
    const float* l1b2 = (const float*)d_in[14];
    const float* ln1g = (const float*)d_in[15];
    const float* ln1b = (const float*)d_in[16];
    const float* gw1  = (const float*)d_in[17];
    const float* gb1  = (const float*)d_in[18];
    const float* gw2  = (const float*)d_in[19];
    const float* gb2  = (const float*)d_in[20];
    const float* cw1  = (const float*)d_in[21];
    const float* cb1  = (const float*)d_in[22];
    const float* cw2  = (const float*)d_in[23];
    const float* cb2  = (const float*)d_in[24];

    char* ws = (char*)d_ws;
    size_t off = 0;
    auto alloc = [&](size_t bytes) {
        void* p = ws + off;
        off += (bytes + 255) & ~(size_t)255;
        return p;
    };
    float* h      = (float*)alloc((size_t)N_NODES * HD * 4);
    unsigned short* h16 = (unsigned short*)alloc((size_t)N_NODES * HD * 2);
    float* z      = (float*)alloc((size_t)N_NODES * HD * 4);
    float* gate   = (float*)alloc((size_t)N_NODES * 4);
    int*   rowptr = (int*)alloc((size_t)(N_NODES + 1) * 4);
    int*   cursor = (int*)alloc((size_t)N_NODES * 4);
    int*   deg    = (int*)alloc((size_t)N_NODES * 4);
    int*   col    = (int*)alloc((size_t)N_EDGES * 4);
    int*   goff   = (int*)alloc((NG + 1) * 4);
    float* pooled = (float*)alloc((size_t)NG * HD * 4);
    int*   bsum   = (int*)alloc(SCAN_NB * 4);
    int*   boff   = (int*)alloc(SCAN_NB * 4);
    short* p_l0w1h = (short*)alloc((size_t)HD * HD * 2);
    short* p_l0w1l = (short*)alloc((size_t)HD * HD * 2);
    short* p_l0w2h = (short*)alloc((size_t)HD * HD * 2);
    short* p_l0w2l = (short*)alloc((size_t)HD * HD * 2);
    short* p_l1w1h = (short*)alloc((size_t)HD * HD * 2);
    short* p_l1w1l = (short*)alloc((size_t)HD * HD * 2);
    short* p_l1w2h = (short*)alloc((size_t)HD * HD * 2);
    short* p_l1w2l = (short*)alloc((size_t)HD * HD * 2);
    short* p_gw1h  = (short*)alloc((size_t)HD * PHD * 2);
    short* p_gw1l  = (short*)alloc((size_t)HD * PHD * 2);

    const int* src = ei;
    const int* dst = ei + N_EDGES;

    build_h_kernel<<<N_NODES, 256, 0, stream>>>(x, emb, h, h16);

    // CSR build (hierarchical scan)
    hipMemsetAsync(deg, 0, (size_t)N_NODES * 4, stream);
    count_deg_kernel<<<(N_EDGES + 255) / 256, 256, 0, stream>>>(dst, deg, N_EDGES);
    deg_bsum_kernel<<<SCAN_NB, 256, 0, stream>>>(deg, bsum);
    scan_bsum_kernel<<<1, 256, 0, stream>>>(bsum, boff, rowptr);
    fill_rowptr_kernel<<<SCAN_NB, 256, 0, stream>>>(deg, boff, rowptr, cursor);
    fill_csr_kernel<<<(N_EDGES + 255) / 256, 256, 0, stream>>>(src, dst, cursor, col, N_EDGES);

    pack_all_kernel<<<144, 256, 0, stream>>>(l0w1, l0w2, l1w1, l1w2, gw1,
                                             p_l0w1h, p_l0w1l, p_l0w2h, p_l0w2l,
                                             p_l1w1h, p_l1w1l, p_l1w2h, p_l1w2l,
                                             p_gw1h, p_gw1l);

    const int mlp_grid = (N_NODES + 63) / 64;

    // GIN block 0
    aggregate_kernel<<<N_NODES / 4, 256, 0, stream>>>(h, h16, rowptr, col, z, N_NODES);
    mlp_mfma_kernel<<<mlp_grid, 256, 0, stream>>>(h, h16, z, p_l0w1h, p_l0w1l, l0b1,
                                                  p_l0w2h, p_l0w2l, l0b2, ln0g, ln0b);
    // GIN block 1
    aggregate_kernel<<<N_NODES / 4, 256, 0, stream>>>(h, h16, rowptr, col, z, N_NODES);
    mlp_mfma_kernel<<<mlp_grid, 256, 0, stream>>>(h, h16, z, p_l1w1h, p_l1w1l, l1b1,
                                                  p_l1w2h, p_l1w2l, l1b2, ln1g, ln1b);

    gate_mfma_kernel<<<mlp_grid, 256, 0, stream>>>(h, p_gw1h, p_gw1l, gb1, gw2, gb2, gate);
    goff_kernel<<<1, 256, 0, stream>>>(bat, goff, N_NODES);
    hipMemsetAsync(pooled, 0, (size_t)NG * HD * 4, stream);
    pool_kernel<<<NG * 4, 256, 0, stream>>>(h, gate, goff, pooled);
    cls_kernel<<<NG, 128, 0, stream>>>(pooled, gf, cw1, cb1, cw2, cb2, (float*)d_out);
}

// Round 9
// 862.720 us; speedup vs baseline: 2.5553x; 1.1894x over previous
//
// GINCombined r9: 2-pass split-bf16 (bf16 weights, corrected activations), 32-row mlp tile (4 blocks/CU)
#include <hip/hip_runtime.h>
#include <math.h>

#define N_NODES 100000
#define N_EDGES 1600000
#define NG      128
#define HD      256
#define PHD     128
#define GFD     32
#define XW      241
#define LN_EPS  1e-5f
#define SCAN_NB 256
#define CHUNK   ((N_NODES + SCAN_NB - 1) / SCAN_NB)   // 391

typedef __attribute__((ext_vector_type(8))) short bf8_t;  // 8 bf16 (4 VGPR)
typedef __attribute__((ext_vector_type(4))) float f4_t;   // 4 f32 acc

static __device__ __forceinline__ float relu_f(float x){ return fmaxf(x, 0.0f); }

static __device__ __forceinline__ unsigned short f2bf_rn(float v) {
    unsigned int u = __float_as_uint(v);
    unsigned int r = (u + 0x7fffu + ((u >> 16) & 1u)) >> 16;
    return (unsigned short)r;
}
static __device__ __forceinline__ float bf2f(unsigned short h) {
    return __uint_as_float((unsigned int)h << 16);
}

// ---------------- h build (fp32 + bf16 mirror) ----------------
__global__ void build_h_kernel(const float* __restrict__ x, const float* __restrict__ emb,
                               float* __restrict__ h, unsigned short* __restrict__ h16)
{
    int node = blockIdx.x;
    int tid  = threadIdx.x;
    const float* xr = x + (size_t)node * XW;
    float v;
    if (tid < 240) {
        v = xr[1 + tid];
    } else {
        int t = (int)xr[0];
        v = emb[t * 16 + (tid - 240)];
    }
    h[(size_t)node * HD + tid] = v;
    h16[(size_t)node * HD + tid] = f2bf_rn(v);
}

// ---------------- CSR build ----------------
__global__ void count_deg_kernel(const int* __restrict__ dst, int* __restrict__ cnt, int e)
{
    int i = blockIdx.x * blockDim.x + threadIdx.x;
    if (i < e) atomicAdd(&cnt[dst[i]], 1);
}

__global__ __launch_bounds__(256) void deg_bsum_kernel(const int* __restrict__ deg, int* __restrict__ bsum)
{
    __shared__ int red[256];
    int b = blockIdx.x, t = threadIdx.x;
    int beg = b * CHUNK, end = beg + CHUNK < N_NODES ? beg + CHUNK : N_NODES;
    int s = 0;
    for (int i = beg + t; i < end; i += 256) s += deg[i];
    red[t] = s; __syncthreads();
    for (int off = 128; off > 0; off >>= 1) {
        if (t < off) red[t] += red[t + off];
        __syncthreads();
    }
    if (t == 0) bsum[b] = red[0];
}

__global__ __launch_bounds__(256) void scan_bsum_kernel(const int* __restrict__ bsum,
                                                        int* __restrict__ boff,
                                                        int* __restrict__ rowptr)
{
    __shared__ int sh[256];
    int t = threadIdx.x;
    sh[t] = bsum[t]; __syncthreads();
    for (int off = 1; off < 256; off <<= 1) {
        int v = sh[t];
        int a = (t >= off) ? sh[t - off] : 0;
        __syncthreads();
        sh[t] = v + a;
        __syncthreads();
    }
    boff[t] = (t > 0) ? sh[t - 1] : 0;
    if (t == 255) rowptr[N_NODES] = sh[255];
}

__global__ __launch_bounds__(256) void fill_rowptr_kernel(const int* __restrict__ deg,
                                                          const int* __restrict__ boff,
                                                          int* __restrict__ rowptr,
                                                          int* __restrict__ cursor)
{
    __shared__ int sh[256];
    int b = blockIdx.x, t = threadIdx.x;
    int beg = b * CHUNK, end = beg + CHUNK < N_NODES ? beg + CHUNK : N_NODES;
    const int per = (CHUNK + 255) / 256;   // 2
    int sbeg = beg + t * per; if (sbeg > end) sbeg = end;
    int send = sbeg + per; if (send > end) send = end;
    int s = 0;
    for (int i = sbeg; i < send; i++) s += deg[i];
    sh[t] = s; __syncthreads();
    for (int off = 1; off < 256; off <<= 1) {
        int v = sh[t];
        int a = (t >= off) ? sh[t - off] : 0;
        __syncthreads();
        sh[t] = v + a;
        __syncthreads();
    }
    int run = boff[b] + ((t > 0) ? sh[t - 1] : 0);
    for (int i = sbeg; i < send; i++) {
        int d = deg[i];
        rowptr[i] = run;
        cursor[i] = run;
        run += d;
    }
}

__global__ void fill_csr_kernel(const int* __restrict__ src, const int* __restrict__ dst,
                                int* __restrict__ cursor, int* __restrict__ col, int e)
{
    int i = blockIdx.x * blockDim.x + threadIdx.x;
    if (i < e) {
        int p = atomicAdd(&cursor[dst[i]], 1);
        col[p] = src[i];
    }
}

// ---------------- aggregate: z = h + sum_neighbors h16 (bf16 gather, 4-way unrolled) ----------------
__global__ __launch_bounds__(256) void aggregate_kernel(
    const float* __restrict__ h, const unsigned short* __restrict__ h16,
    const int* __restrict__ rowptr, const int* __restrict__ col,
    float* __restrict__ z, int n)
{
    int node = blockIdx.x * 4 + (threadIdx.x >> 6);
    int lane = threadIdx.x & 63;
    if (node >= n) return;
    const int l4 = lane * 4;
    size_t base = (size_t)node * HD + l4;
    float4 a0 = *(const float4*)&h[base];   // self term exact (fp32)
    float4 a1 = make_float4(0,0,0,0), a2 = make_float4(0,0,0,0), a3 = make_float4(0,0,0,0);
    int e = rowptr[node], e1 = rowptr[node + 1];
    for (; e + 4 <= e1; e += 4) {
        int s0 = col[e], s1 = col[e+1], s2 = col[e+2], s3 = col[e+3];
        ushort4 u0 = *(const ushort4*)&h16[(size_t)s0 * HD + l4];
        ushort4 u1 = *(const ushort4*)&h16[(size_t)s1 * HD + l4];
        ushort4 u2 = *(const ushort4*)&h16[(size_t)s2 * HD + l4];
        ushort4 u3 = *(const ushort4*)&h16[(size_t)s3 * HD + l4];
        a0.x += bf2f(u0.x); a0.y += bf2f(u0.y); a0.z += bf2f(u0.z); a0.w += bf2f(u0.w);
        a1.x += bf2f(u1.x); a1.y += bf2f(u1.y); a1.z += bf2f(u1.z); a1.w += bf2f(u1.w);
        a2.x += bf2f(u2.x); a2.y += bf2f(u2.y); a2.z += bf2f(u2.z); a2.w += bf2f(u2.w);
        a3.x += bf2f(u3.x); a3.y += bf2f(u3.y); a3.z += bf2f(u3.z); a3.w += bf2f(u3.w);
    }
    for (; e < e1; e++) {
        int s = col[e];
        ushort4 u = *(const ushort4*)&h16[(size_t)s * HD + l4];
        a0.x += bf2f(u.x); a0.y += bf2f(u.y); a0.z += bf2f(u.z); a0.w += bf2f(u.w);
    }
    a0.x += a1.x + a2.x + a3.x;
    a0.y += a1.y + a2.y + a3.y;
    a0.z += a1.z + a2.z + a3.z;
    a0.w += a1.w + a2.w + a3.w;
    *(float4*)&z[base] = a0;
}

// ---------------- merged weight packing (hi only now) ----------------
static __device__ __forceinline__ void pack_one(const float* __restrict__ w, short* __restrict__ hi,
                                                int N, int fbase)
{
    int lane = threadIdx.x & 63;
    int f = fbase * 4 + (threadIdx.x >> 6);
    const int KB = 8;            // K=256 always
    int nb = f / KB, kb = f % KB;
    int n = nb * 16 + (lane & 15);
    int k0 = kb * 32 + (lane >> 4) * 8;
    size_t o = (size_t)f * 512 + lane * 8;
    #pragma unroll
    for (int j = 0; j < 8; j++) {
        float v = w[(size_t)(k0 + j) * N + n];
        hi[o + j] = (short)f2bf_rn(v);
    }
}

__global__ __launch_bounds__(256) void pack_all_kernel(
    const float* __restrict__ w0, const float* __restrict__ w1,
    const float* __restrict__ w2, const float* __restrict__ w3,
    const float* __restrict__ w4,
    short* o0h, short* o1h, short* o2h, short* o3h, short* o4h)
{
    int b = blockIdx.x;
    if      (b < 32)  pack_one(w0, o0h, HD,  b);
    else if (b < 64)  pack_one(w1, o1h, HD,  b - 32);
    else if (b < 96)  pack_one(w2, o2h, HD,  b - 64);
    else if (b < 128) pack_one(w3, o3h, HD,  b - 96);
    else              pack_one(w4, o4h, PHD, b - 128);
}

// 32-row split matmul: acc += (Ahi+Alo)@Bh  (bf16 weights, corrected activations)
// A hi at buf[0:16K), lo at buf[16K:32K), swizzled.
static __device__ __forceinline__ void mm32(
    f4_t (&acc)[2][4], const char* buf,
    const short* __restrict__ Bh,
    int wc, int cb, int kg, int lane)
{
    bf8_t bcur[4], bnxt[4];
    #pragma unroll
    for (int ni = 0; ni < 4; ni++)
        bcur[ni] = *(const bf8_t*)&Bh[((size_t)((wc*4+ni)*8))*512 + lane*8];
    for (int kb = 0; kb < 8; kb++) {
        if (kb < 7) {
            #pragma unroll
            for (int ni = 0; ni < 4; ni++)
                bnxt[ni] = *(const bf8_t*)&Bh[((size_t)((wc*4+ni)*8 + kb+1))*512 + lane*8];
        }
        bf8_t ahi[2], alo[2];
        #pragma unroll
        for (int mi = 0; mi < 2; mi++) {
            int row = mi*16 + cb;
            int byte = (row*512 + kb*64 + kg*16) ^ ((row & 7) << 4);
            ahi[mi] = *(const bf8_t*)(buf + byte);
            alo[mi] = *(const bf8_t*)(buf + 16384 + byte);
        }
        #pragma unroll
        for (int mi = 0; mi < 2; mi++)
            #pragma unroll
            for (int ni = 0; ni < 4; ni++)
                acc[mi][ni] = __builtin_amdgcn_mfma_f32_16x16x32_bf16(ahi[mi], bcur[ni], acc[mi][ni], 0, 0, 0);
        #pragma unroll
        for (int mi = 0; mi < 2; mi++)
            #pragma unroll
            for (int ni = 0; ni < 4; ni++)
                acc[mi][ni] = __builtin_amdgcn_mfma_f32_16x16x32_bf16(alo[mi], bcur[ni], acc[mi][ni], 0, 0, 0);
        #pragma unroll
        for (int ni = 0; ni < 4; ni++) bcur[ni] = bnxt[ni];
    }
}

// ---------------- fused MLP + LN + residual (32 rows/block, 32KB LDS, 4 blocks/CU) ----------------
__global__ __launch_bounds__(256, 4) void mlp_mfma_kernel(
    float* __restrict__ h, unsigned short* __restrict__ h16, const float* __restrict__ z,
    const short* __restrict__ w1h, const float* __restrict__ b1,
    const short* __restrict__ w2h, const float* __restrict__ b2,
    const float* __restrict__ lng, const float* __restrict__ lnb)
{
    __shared__ char buf[32768];
    const int tid  = threadIdx.x;
    const int lane = tid & 63;
    const int wv   = tid >> 6;      // 0..3 (column group)
    const int cb   = lane & 15;
    const int kg   = lane >> 4;
    const long row0 = (long)blockIdx.x * 32;

    // ---- stage z tile [32][256]: split hi/lo, swizzled (8 rows per wave) ----
    for (int rr = 0; rr < 8; rr++) {
        int row = wv * 8 + rr;
        long grow = row0 + row;
        float4 v = make_float4(0.f, 0.f, 0.f, 0.f);
        if (grow < N_NODES) v = *(const float4*)&z[grow * HD + lane * 4];
        ushort4 hi4, lo4;
        unsigned short hb;
        hb = f2bf_rn(v.x); hi4.x = hb; lo4.x = f2bf_rn(v.x - bf2f(hb));
        hb = f2bf_rn(v.y); hi4.y = hb; lo4.y = f2bf_rn(v.y - bf2f(hb));
        hb = f2bf_rn(v.z); hi4.z = hb; lo4.z = f2bf_rn(v.z - bf2f(hb));
        hb = f2bf_rn(v.w); hi4.w = hb; lo4.w = f2bf_rn(v.w - bf2f(hb));
        int byte = (row * 512 + lane * 8) ^ ((row & 7) << 4);
        *(ushort4*)(buf + byte)         = hi4;
        *(ushort4*)(buf + 16384 + byte) = lo4;
    }
    __syncthreads();

    f4_t acc[2][4];
    const f4_t zero4 = {0.f, 0.f, 0.f, 0.f};
    #pragma unroll
    for (int mi = 0; mi < 2; mi++)
        #pragma unroll
        for (int ni = 0; ni < 4; ni++) acc[mi][ni] = zero4;

    mm32(acc, buf, w1h, wv, cb, kg, lane);
    __syncthreads();

    // ---- t = relu(acc + b1) -> hi/lo swizzled back into buf ----
    {
        float bias1[4];
        #pragma unroll
        for (int ni = 0; ni < 4; ni++) bias1[ni] = b1[wv * 64 + ni * 16 + cb];
        #pragma unroll
        for (int mi = 0; mi < 2; mi++) {
            #pragma unroll
            for (int ni = 0; ni < 4; ni++) {
                int colx2 = (wv * 64 + ni * 16 + cb) * 2;
                #pragma unroll
                for (int j = 0; j < 4; j++) {
                    float t = relu_f(acc[mi][ni][j] + bias1[ni]);
                    int row = mi * 16 + kg * 4 + j;
                    unsigned short hb = f2bf_rn(t);
                    unsigned short lb = f2bf_rn(t - bf2f(hb));
                    int byte = (row * 512 + colx2) ^ ((row & 7) << 4);
                    *(short*)(buf + byte)         = (short)hb;
                    *(short*)(buf + 16384 + byte) = (short)lb;
                }
            }
        }
    }
    __syncthreads();

    #pragma unroll
    for (int mi = 0; mi < 2; mi++)
        #pragma unroll
        for (int ni = 0; ni < 4; ni++) acc[mi][ni] = zero4;

    mm32(acc, buf, w2h, wv, cb, kg, lane);
    __syncthreads();

    // ---- z2 = acc + b2 -> f32 [32][256] over whole buf (64B-chunk swizzle) ----
    {
        float bias2[4];
        #pragma unroll
        for (int ni = 0; ni < 4; ni++) bias2[ni] = b2[wv * 64 + ni * 16 + cb];
        #pragma unroll
        for (int mi = 0; mi < 2; mi++) {
            #pragma unroll
            for (int ni = 0; ni < 4; ni++) {
                int col = wv * 64 + ni * 16 + cb;
                #pragma unroll
                for (int j = 0; j < 4; j++) {
                    int row = mi * 16 + kg * 4 + j;
                    int byte = (row * 1024 + col * 4) ^ (((row >> 2) & 3) << 6);
                    *(float*)(buf + byte) = acc[mi][ni][j] + bias2[ni];
                }
            }
        }
    }
    __syncthreads();

    // ---- LN + relu + residual; write h fp32 + h16 mirror (8 rows per wave) ----
    {
        const float4 gv = *(const float4*)&lng[lane * 4];
        const float4 bv = *(const float4*)&lnb[lane * 4];
        for (int rr = 0; rr < 8; rr++) {
            int row = wv * 8 + rr;
            long grow = row0 + row;
            if (grow >= N_NODES) break;
            int byte = (row * 1024 + lane * 16) ^ (((row >> 2) & 3) << 6);
            float4 v = *(const float4*)(buf + byte);
            float s = v.x + v.y + v.z + v.w;
            float q = v.x * v.x + v.y * v.y + v.z * v.z + v.w * v.w;
            #pragma unroll
            for (int off = 32; off > 0; off >>= 1) {
                s += __shfl_xor(s, off, 64);
                q += __shfl_xor(q, off, 64);
            }
            float mu = s * (1.0f / 256.0f);
            float var = q * (1.0f / 256.0f) - mu * mu;
            float rstd = rsqrtf(var + LN_EPS);
            size_t gi = (size_t)grow * HD + lane * 4;
            float4 hv = *(float4*)&h[gi];
            hv.x += relu_f((v.x - mu) * rstd * gv.x + bv.x);
            hv.y += relu_f((v.y - mu) * rstd * gv.y + bv.y);
            hv.z += relu_f((v.z - mu) * rstd * gv.z + bv.z);
            hv.w += relu_f((v.w - mu) * rstd * gv.w + bv.w);
            *(float4*)&h[gi] = hv;
            ushort4 m16;
            m16.x = f2bf_rn(hv.x); m16.y = f2bf_rn(hv.y);
            m16.z = f2bf_rn(hv.z); m16.w = f2bf_rn(hv.w);
            *(ushort4*)&h16[gi] = m16;
        }
    }
}

// ---------------- gate via split-bf16 MFMA (64 rows/block, 2-pass) ----------------
__global__ __launch_bounds__(256, 2) void gate_mfma_kernel(
    const float* __restrict__ h,
    const short* __restrict__ g1h, const float* __restrict__ gb1,
    const float* __restrict__ gw2, const float* __restrict__ gb2,
    float* __restrict__ gate)
{
    __shared__ char buf[65536];
    const int tid  = threadIdx.x;
    const int lane = tid & 63;
    const int wv   = tid >> 6;
    const int cb   = lane & 15;
    const int kg   = lane >> 4;
    const long row0 = (long)blockIdx.x * 64;

    for (int rr = 0; rr < 16; rr++) {
        int row = wv * 16 + rr;
        long grow = row0 + row;
        float4 v = make_float4(0.f, 0.f, 0.f, 0.f);
        if (grow < N_NODES) v = *(const float4*)&h[grow * HD + lane * 4];
        ushort4 hi4, lo4;
        unsigned short hb;
        hb = f2bf_rn(v.x); hi4.x = hb; lo4.x = f2bf_rn(v.x - bf2f(hb));
        hb = f2bf_rn(v.y); hi4.y = hb; lo4.y = f2bf_rn(v.y - bf2f(hb));
        hb = f2bf_rn(v.z); hi4.z = hb; lo4.z = f2bf_rn(v.z - bf2f(hb));
        hb = f2bf_rn(v.w); hi4.w = hb; lo4.w = f2bf_rn(v.w - bf2f(hb));
        int byte = (row * 512 + lane * 8) ^ ((row & 7) << 4);
        *(ushort4*)(buf + byte)         = hi4;
        *(ushort4*)(buf + 32768 + byte) = lo4;
    }
    __syncthreads();

    f4_t acc[4][2];
    const f4_t zero4 = {0.f, 0.f, 0.f, 0.f};
    #pragma unroll
    for (int mi = 0; mi < 4; mi++) { acc[mi][0] = zero4; acc[mi][1] = zero4; }

    #pragma unroll
    for (int pass = 0; pass < 2; pass++) {
        const char* Abase = (pass == 1) ? (buf + 32768) : buf;
        for (int kb = 0; kb < 8; kb++) {
            bf8_t a[4], b[2];
            #pragma unroll
            for (int mi = 0; mi < 4; mi++) {
                int row = mi * 16 + cb;
                int byte = (row * 512 + kb * 64 + kg * 16) ^ ((row & 7) << 4);
                a[mi] = *(const bf8_t*)(Abase + byte);
            }
            #pragma unroll
            for (int ni = 0; ni < 2; ni++) {
                int nb = wv * 2 + ni;
                b[ni] = *(const bf8_t*)&g1h[(size_t)(nb * 8 + kb) * 512 + lane * 8];
            }
            #pragma unroll
            for (int mi = 0; mi < 4; mi++)
                #pragma unroll
                for (int ni = 0; ni < 2; ni++)
                    acc[mi][ni] = __builtin_amdgcn_mfma_f32_16x16x32_bf16(a[mi], b[ni], acc[mi][ni], 0, 0, 0);
        }
    }
    __syncthreads();

    {
        float* G1 = (float*)buf;
        float bias1[2];
        bias1[0] = gb1[wv * 32 + cb];
        bias1[1] = gb1[wv * 32 + 16 + cb];
        #pragma unroll
        for (int mi = 0; mi < 4; mi++) {
            #pragma unroll
            for (int ni = 0; ni < 2; ni++) {
                int colv = wv * 32 + ni * 16 + cb;
                #pragma unroll
                for (int j = 0; j < 4; j++) {
                    int row = mi * 16 + kg * 4 + j;
                    G1[row * PHD + colv] = relu_f(acc[mi][ni][j] + bias1[ni]);
                }
            }
        }
    }
    __syncthreads();

    {
        const float* G1 = (const float*)buf;
        float2 wv2 = *(const float2*)&gw2[lane * 2];
        float b2v = gb2[0];
        for (int rr = 0; rr < 16; rr++) {
            int row = wv * 16 + rr;
            long grow = row0 + row;
            if (grow >= N_NODES) break;
            float2 t2 = *(const float2*)&G1[row * PHD + lane * 2];
            float p = t2.x * wv2.x + t2.y * wv2.y;
            #pragma unroll
            for (int off = 32; off > 0; off >>= 1) p += __shfl_xor(p, off, 64);
            if (lane == 0) gate[grow] = p + b2v;
        }
    }
}

// ---------------- graph offsets ----------------
__global__ void goff_kernel(const int* __restrict__ batch, int* __restrict__ goff, int n)
{
    int t = threadIdx.x;
    if (t > NG) return;
    int lo = 0, hi = n;
    while (lo < hi) {
        int mid = (lo + hi) >> 1;
        if (batch[mid] < t) lo = mid + 1; else hi = mid;
    }
    goff[t] = lo;
}

// ---------------- softmax-weighted pooling (4 blocks per graph, atomic accumulate) ----------------
__global__ __launch_bounds__(256) void pool_kernel(
    const float* __restrict__ h, const float* __restrict__ gate,
    const int* __restrict__ goff, float* __restrict__ pooled)
{
    __shared__ float red[256];
    __shared__ float m_sh, s_sh;
    int g = blockIdx.x >> 2, q = blockIdx.x & 3;
    int tid = threadIdx.x;
    int beg = goff[g], end = goff[g + 1];
    if (beg >= end) return;   // pooled pre-zeroed

    float lm = -3.4e38f;
    for (int i = beg + tid; i < end; i += 256) lm = fmaxf(lm, gate[i]);
    red[tid] = lm; __syncthreads();
    for (int off = 128; off > 0; off >>= 1) {
        if (tid < off) red[tid] = fmaxf(red[tid], red[tid + off]);
        __syncthreads();
    }
    if (tid == 0) m_sh = red[0];
    __syncthreads();
    float m = m_sh;

    float ls = 0.0f;
    for (int i = beg + tid; i < end; i += 256) ls += expf(gate[i] - m);
    __syncthreads();
    red[tid] = ls; __syncthreads();
    for (int off = 128; off > 0; off >>= 1) {
        if (tid < off) red[tid] += red[tid + off];
        __syncthreads();
    }
    if (tid == 0) s_sh = red[0];
    __syncthreads();
    float inv_s = 1.0f / s_sh;

    float acc = 0.0f;
    for (int i = beg + q; i < end; i += 4) {
        float a = expf(gate[i] - m);
        acc += a * h[(size_t)i * HD + tid];
    }
    atomicAdd(&pooled[(size_t)g * HD + tid], acc * inv_s);
}

// ---------------- classifier ----------------
__global__ __launch_bounds__(128) void cls_kernel(
    const float* __restrict__ pooled, const float* __restrict__ gf,
    const float* __restrict__ w1, const float* __restrict__ b1,
    const float* __restrict__ w2, const float* __restrict__ b2,
    float* __restrict__ out)
{
    __shared__ float r0[128], r1[128];
    int g = blockIdx.x, c = threadIdx.x;
    float acc = b1[c];
    const float* pr = pooled + (size_t)g * HD;
    for (int k = 0; k < HD; k++) acc += pr[k] * w1[k * PHD + c];
    const float* gr = gf + g * GFD;
    for (int k = 0; k < GFD; k++) acc += gr[k] * w1[(HD + k) * PHD + c];
    float t = relu_f(acc);
    r0[c] = t * w2[c * 2 + 0];
    r1[c] = t * w2[c * 2 + 1];
    __syncthreads();
    for (int off = 64; off > 0; off >>= 1) {
        if (c < off) { r0[c] += r0[c + off]; r1[c] += r1[c + off]; }
        __syncthreads();
    }
    if (c == 0) {
        out[g * 2 + 0] = r0[0] + b2[0];
        out[g * 2 + 1] = r1[0] + b2[1];
    }
}

extern "C" void kernel_launch(void* const* d_in, const int* in_sizes, int n_in,
                              void* d_out, int out_size, void* d_ws, size_t ws_size,
                              hipStream_t stream)
{
    const float* x    = (const float*)d_in[0];
    const int*   ei   = (const int*)d_in[1];
    const int*   bat  = (const int*)d_in[2];
    const float* gf   = (const float*)d_in[3];
    const float* emb  = (const float*)d_in[4];
    const float* l0w1 = (const float*)d_in[5];
    const float* l0b1 = (const float*)d_in[6];
    const float* l0w2 = (const float*)d_in[7];
    const float* l0b2 = (const float*)d_in[8];
    const float* ln0g = (const float*)d_in[9];
    const float* ln0b = (const float*)d_in[10];
    const float* l1w1 = (const float*)d_in[11];
    const float* l1b1 = (const float*)d_in[12];
    const float* l1w2 = (const float*)d_in[13];
    const float* l1b2 = (const float*)d_in[14];
    const float* ln1g = (const float*)d_in[15];
    const float* ln1b = (const float*)d_in[16];
    const float* gw1  = (const float*)d_in[17];
    const float* gb1  = (const float*)d_in[18];
    const float* gw2  = (const float*)d_in[19];
    const float* gb2  = (const float*)d_in[20];
    const float* cw1  = (const float*)d_in[21];
    const float* cb1  = (const float*)d_in[22];
    const float* cw2  = (const float*)d_in[23];
    const float* cb2  = (const float*)d_in[24];

    char* ws = (char*)d_ws;
    size_t off = 0;
    auto alloc = [&](size_t bytes) {
        void* p = ws + off;
        off += (bytes + 255) & ~(size_t)255;
        return p;
    };
    float* h      = (float*)alloc((size_t)N_NODES * HD * 4);
    unsigned short* h16 = (unsigned short*)alloc((size_t)N_NODES * HD * 2);
    float* z      = (float*)alloc((size_t)N_NODES * HD * 4);
    float* gate   = (float*)alloc((size_t)N_NODES * 4);
    int*   rowptr = (int*)alloc((size_t)(N_NODES + 1) * 4);
    int*   cursor = (int*)alloc((size_t)N_NODES * 4);
    int*   deg    = (int*)alloc((size_t)N_NODES * 4);
    int*   col    = (int*)alloc((size_t)N_EDGES * 4);
    int*   goff   = (int*)alloc((NG + 1) * 4);
    float* pooled = (float*)alloc((size_t)NG * HD * 4);
    int*   bsum   = (int*)alloc(SCAN_NB * 4);
    int*   boff   = (int*)alloc(SCAN_NB * 4);
    short* p_l0w1h = (short*)alloc((size_t)HD * HD * 2);
    short* p_l0w2h = (short*)alloc((size_t)HD * HD * 2);
    short* p_l1w1h = (short*)alloc((size_t)HD * HD * 2);
    short* p_l1w2h = (short*)alloc((size_t)HD * HD * 2);
    short* p_gw1h  = (short*)alloc((size_t)HD * PHD * 2);

    const int* src = ei;
    const int* dst = ei + N_EDGES;

    build_h_kernel<<<N_NODES, 256, 0, stream>>>(x, emb, h, h16);

    // CSR build (hierarchical scan)
    hipMemsetAsync(deg, 0, (size_t)N_NODES * 4, stream);
    count_deg_kernel<<<(N_EDGES + 255) / 256, 256, 0, stream>>>(dst, deg, N_EDGES);
    deg_bsum_kernel<<<SCAN_NB, 256, 0, stream>>>(deg, bsum);
    scan_bsum_kernel<<<1, 256, 0, stream>>>(bsum, boff, rowptr);
    fill_rowptr_kernel<<<SCAN_NB, 256, 0, stream>>>(deg, boff, rowptr, cursor);
    fill_csr_kernel<<<(N_EDGES + 255) / 256, 256, 0, stream>>>(src, dst, cursor, col, N_EDGES);

    pack_all_kernel<<<144, 256, 0, stream>>>(l0w1, l0w2, l1w1, l1w2, gw1,
                                             p_l0w1h, p_l0w2h, p_l1w1h, p_l1w2h, p_gw1h);

    const int mlp_grid = (N_NODES + 31) / 32;   // 3125

    // GIN block 0
    aggregate_kernel<<<N_NODES / 4, 256, 0, stream>>>(h, h16, rowptr, col, z, N_NODES);
    mlp_mfma_kernel<<<mlp_grid, 256, 0, stream>>>(h, h16, z, p_l0w1h, l0b1,
                                                  p_l0w2h, l0b2, ln0g, ln0b);
    // GIN block 1
    aggregate_kernel<<<N_NODES / 4, 256, 0, stream>>>(h, h16, rowptr, col, z, N_NODES);
    mlp_mfma_kernel<<<mlp_grid, 256, 0, stream>>>(h, h16, z, p_l1w1h, l1b1,
                                                  p_l1w2h, l1b2, ln1g, ln1b);

    gate_mfma_kernel<<<(N_NODES + 63) / 64, 256, 0, stream>>>(h, p_gw1h, gb1, gw2, gb2, gate);
    goff_kernel<<<1, 256, 0, stream>>>(bat, goff, N_NODES);
    hipMemsetAsync(pooled, 0, (size_t)NG * HD * 4, stream);
    pool_kernel<<<NG * 4, 256, 0, stream>>>(h, gate, goff, pooled);
    cls_kernel<<<NG, 128, 0, stream>>>(pooled, gf, cw1, cb1, cw2, cb2, (float*)d_out);
}